// Round 14
// baseline (271.746 us; speedup 1.0000x reference)
//
#include <hip/hip_runtime.h>
#include <cfloat>
#include <cstddef>

#define B_SZ 16384
#define DIN  784
#define H_SZ 400
#define D_SZ 512
#define K_SZ 8192

#define DIN_P 800   // 784 padded to 25*32
#define H_P   416   // 400 padded to 13*32

#define ZSCALE 64.f
#define ESCALE 256.f
#define SQSCALE (ZSCALE * ESCALE)

typedef short bf16x8 __attribute__((ext_vector_type(8)));
typedef float f32x4  __attribute__((ext_vector_type(4)));
typedef int   i32x4  __attribute__((ext_vector_type(4)));
typedef int   i32x8  __attribute__((ext_vector_type(8)));

__device__ __forceinline__ unsigned short f2bf(float f) {
  unsigned u = __float_as_uint(f);
  unsigned r = (u + 0x7FFFu + ((u >> 16) & 1u)) >> 16;
  return (unsigned short)r;
}
__device__ __forceinline__ float bf2f(unsigned short h) {
  return __uint_as_float(((unsigned)h) << 16);
}
// fp32 -> OCP e4m3fn (RNE in normal range, RN in subnormal, clamp to 448)
__device__ __forceinline__ unsigned f2e4m3(float f) {
  unsigned u = __float_as_uint(f);
  const unsigned sign = (u >> 24) & 0x80u;
  const float af = __uint_as_float(u & 0x7FFFFFFFu);
  if (af >= 448.f) return sign | 0x7Eu;
  if (af < 0.015625f) {                  // subnormal, unit 2^-9
    const int m = (int)(af * 512.f + 0.5f);
    return sign | (unsigned)m;
  }
  u = (u & 0x7FFFFFFFu) + 0x7FFFFu + ((u >> 20) & 1u);
  const unsigned e8 = (u >> 23) - 120u;  // -127+7
  if (e8 >= 16u) return sign | 0x7Eu;
  return sign | (e8 << 3) | ((u >> 20) & 7u);
}

// ---------------------------------------------------------------------------
// Fused emb prep: one pass over emb producing bf16 copy (decode gather),
// fp8*ESCALE copy (VQ scan), esqh = 0.5*SQSCALE*||e||^2, + zero accumulators.
// One wave per codebook row.
// ---------------------------------------------------------------------------
__global__ __launch_bounds__(256)
void embprep_kernel(const float* __restrict__ emb,
                    unsigned short* __restrict__ embb,
                    unsigned char* __restrict__ embf,
                    float* __restrict__ esqh, float* __restrict__ accum) {
  if (blockIdx.x == 0 && threadIdx.x == 0) { accum[0] = 0.f; accum[1] = 0.f; }
  const int row  = blockIdx.x * 4 + (threadIdx.x >> 6);
  const int lane = threadIdx.x & 63;
  const float* p = emb + (size_t)row * D_SZ + lane * 8;
  const float4 v0 = *reinterpret_cast<const float4*>(p);
  const float4 v1 = *reinterpret_cast<const float4*>(p + 4);

  ushort4 h0, h1;
  h0.x = f2bf(v0.x); h0.y = f2bf(v0.y); h0.z = f2bf(v0.z); h0.w = f2bf(v0.w);
  h1.x = f2bf(v1.x); h1.y = f2bf(v1.y); h1.z = f2bf(v1.z); h1.w = f2bf(v1.w);
  reinterpret_cast<ushort4*>(embb + (size_t)row * D_SZ + lane * 8)[0] = h0;
  reinterpret_cast<ushort4*>(embb + (size_t)row * D_SZ + lane * 8 + 4)[0] = h1;

  uint2 q;
  q.x = f2e4m3(v0.x * ESCALE) | (f2e4m3(v0.y * ESCALE) << 8) |
        (f2e4m3(v0.z * ESCALE) << 16) | (f2e4m3(v0.w * ESCALE) << 24);
  q.y = f2e4m3(v1.x * ESCALE) | (f2e4m3(v1.y * ESCALE) << 8) |
        (f2e4m3(v1.z * ESCALE) << 16) | (f2e4m3(v1.w * ESCALE) << 24);
  *reinterpret_cast<uint2*>(embf + (size_t)row * D_SZ + lane * 8) = q;

  float s = v0.x * v0.x + v0.y * v0.y + v0.z * v0.z + v0.w * v0.w +
            v1.x * v1.x + v1.y * v1.y + v1.z * v1.z + v1.w * v1.w;
#pragma unroll
  for (int off = 32; off > 0; off >>= 1) s += __shfl_down(s, off);
  if (lane == 0) esqh[row] = 0.5f * SQSCALE * s;
}

// ---------------------------------------------------------------------------
// x [16384][784] fp32 -> xb [16384][800] bf16, zero-padded cols 784..799
// ---------------------------------------------------------------------------
__global__ __launch_bounds__(256)
void castpad_x_kernel(const float* __restrict__ x, unsigned short* __restrict__ xb) {
  int u = blockIdx.x * 256 + threadIdx.x;
  const int total = B_SZ * 200;
  const int stride = gridDim.x * 256;
  for (; u < total; u += stride) {
    const int row = u / 200, c4 = u - row * 200;
    ushort4 o = make_ushort4(0, 0, 0, 0);
    if (c4 < 196) {
      float4 v = *reinterpret_cast<const float4*>(x + (size_t)row * DIN + c4 * 4);
      o.x = f2bf(v.x); o.y = f2bf(v.y); o.z = f2bf(v.z); o.w = f2bf(v.w);
    }
    *reinterpret_cast<ushort4*>(xb + (size_t)row * DIN_P + c4 * 4) = o;
  }
}

// ---------------------------------------------------------------------------
// W [K][N] fp32 -> Wt [Npad][Kpad] bf16, zero-padded, LDS-tiled transpose.
// ---------------------------------------------------------------------------
__global__ __launch_bounds__(256)
void wtrans_kernel(const float* __restrict__ W, unsigned short* __restrict__ Wt,
                   int K, int N, int Kpad, int Npad) {
  __shared__ float t[32][33];
  const int tx = threadIdx.x & 31, ty = threadIdx.x >> 5;
  const int k0 = blockIdx.x * 32, n0 = blockIdx.y * 32;
#pragma unroll
  for (int s = 0; s < 4; ++s) {
    const int k = k0 + ty + s * 8, n = n0 + tx;
    t[ty + s * 8][tx] = (k < K && n < N) ? W[(size_t)k * N + n] : 0.f;
  }
  __syncthreads();
#pragma unroll
  for (int s = 0; s < 4; ++s) {
    const int n = n0 + ty + s * 8, k = k0 + tx;
    if (n < Npad && k < Kpad)
      Wt[(size_t)n * Kpad + k] = f2bf(t[tx][ty + s * 8]);
  }
}

// ---------------------------------------------------------------------------
// MFMA GEMM: C = act(A @ Bt^T + bias).  BM=BN=128, BK=32, 4 waves (2x2),
// acc 4x4 of 16x16x32 bf16 fragments, double-buffered global_load_lds.
// ACT: 0=none 1=relu 2=sigmoid (fast: p=rcp(1+exp2(-v*log2e))).
// BCE fused via (x-1)*v - ln(1+e^-v): one v_exp_f32 + one v_log_f32.
// XCD-chunked block swizzle: bid=(d%8)*(nwg/8)+d/8.
// ---------------------------------------------------------------------------
template <int ACT, bool GATHER, bool BCE, bool OUTF32, bool FP8OUT>
__global__ __launch_bounds__(256, 3)
void mgemm_kernel(const unsigned short* __restrict__ A,
                  const unsigned short* __restrict__ Bt,
                  const float* __restrict__ bias, void* __restrict__ C,
                  int N, int Kpad, int NpadOut,
                  const int* __restrict__ gidx,
                  const float* __restrict__ xg, float* __restrict__ loss_accum,
                  unsigned char* __restrict__ C8) {
  __shared__ __align__(16) unsigned short As[2][128 * 32];
  __shared__ __align__(16) unsigned short Bs[2][128 * 32];
  __shared__ int   sidx[128];
  __shared__ float rsum[256];

  const int tid  = threadIdx.x;
  const int w    = tid >> 6, lane = tid & 63;
  const int wr   = w >> 1, wc = w & 1;

  // XCD-chunked swizzle (nwg % 8 == 0 for all call sites: 512, 896)
  const int nwg = gridDim.x * gridDim.y;
  int bid = blockIdx.y * gridDim.x + blockIdx.x;
  bid = (bid & 7) * (nwg >> 3) + (bid >> 3);
  const int bx = bid % gridDim.x, by = bid / gridDim.x;
  const int rowBase = by * 128, colBase = bx * 128;

  if (GATHER) {
    if (tid < 128) sidx[tid] = gidx[rowBase + tid];
    __syncthreads();
  }

  const int srow  = lane >> 2;
  const int sunit = lane & 3;

  auto stageA = [&](int kt, int bb) {
#pragma unroll
    for (int c = 0; c < 2; ++c) {
      const int rowq = (c * 4 + w) * 16 + srow;
      const long arow = GATHER ? (long)sidx[rowq] : (long)(rowBase + rowq);
      const unsigned short* g = A + (size_t)arow * Kpad + kt * 32 + sunit * 8;
      __builtin_amdgcn_global_load_lds(
          (const __attribute__((address_space(1))) unsigned int*)g,
          (__attribute__((address_space(3))) unsigned int*)
              &As[bb][(((c * 4 + w) * 64) + lane) * 8],
          16, 0, 0);
    }
  };
  auto stageB = [&](int kt, int bb) {
#pragma unroll
    for (int c = 0; c < 2; ++c) {
      const int rowq = (c * 4 + w) * 16 + srow;
      const unsigned short* g =
          Bt + (size_t)(colBase + rowq) * Kpad + kt * 32 + sunit * 8;
      __builtin_amdgcn_global_load_lds(
          (const __attribute__((address_space(1))) unsigned int*)g,
          (__attribute__((address_space(3))) unsigned int*)
              &Bs[bb][(((c * 4 + w) * 64) + lane) * 8],
          16, 0, 0);
    }
  };

  f32x4 acc[4][4] = {};
  stageA(0, 0); stageB(0, 0);
  const int nk = Kpad >> 5;
  const int lr = lane >> 4, lc = lane & 15;

  for (int kt = 0; kt < nk; ++kt) {
    const int bb = kt & 1;
    __syncthreads();
    if (kt + 1 < nk) { stageA(kt + 1, bb ^ 1); stageB(kt + 1, bb ^ 1); }
    bf16x8 a[4], b[4];
#pragma unroll
    for (int f = 0; f < 4; ++f) {
      const int ra = wr * 64 + f * 16 + lc;
      a[f] = *reinterpret_cast<const bf16x8*>(&As[bb][ra * 32 + lr * 8]);
      const int rb = wc * 64 + f * 16 + lc;
      b[f] = *reinterpret_cast<const bf16x8*>(&Bs[bb][rb * 32 + lr * 8]);
    }
#pragma unroll
    for (int i = 0; i < 4; ++i)
#pragma unroll
      for (int j = 0; j < 4; ++j)
        acc[i][j] =
            __builtin_amdgcn_mfma_f32_16x16x32_bf16(a[i], b[j], acc[i][j], 0, 0, 0);
  }

  float bce = 0.f;
#pragma unroll
  for (int j = 0; j < 4; ++j) {
    const int gcol = colBase + wc * 64 + j * 16 + lc;
    const float bj = (gcol < N) ? bias[gcol] : 0.f;
#pragma unroll
    for (int i = 0; i < 4; ++i) {
      const int growb = rowBase + wr * 64 + i * 16 + lr * 4;
#pragma unroll
      for (int r = 0; r < 4; ++r) {
        float v = acc[i][j][r] + bj;
        if (ACT == 1) v = fmaxf(v, 0.f);
        float e2 = 0.f, ov = v;
        if (ACT == 2) {
          e2 = __builtin_amdgcn_exp2f(v * -1.442695041f);   // exp(-v)
          ov = __builtin_amdgcn_rcpf(1.f + e2);             // sigmoid
        }
        const int grow = growb + r;
        if (OUTF32) {
          if (gcol < N) {
            ((float*)C)[(size_t)grow * N + gcol] = ov;
            if (BCE) {
              // x*log(p)+(1-x)*log(1-p) = (x-1)*v - ln(1+e^-v)
              const float L =
                  0.69314718056f * __builtin_amdgcn_logf(1.f + e2);
              const float xv = xg[(size_t)grow * N + gcol];
              bce += (xv - 1.f) * v - L;
            }
          }
        } else {
          if (gcol < NpadOut) {
            const unsigned short hv = (gcol < N) ? f2bf(ov) : (unsigned short)0;
            ((unsigned short*)C)[(size_t)grow * NpadOut + gcol] = hv;
            if (FP8OUT)
              C8[(size_t)grow * NpadOut + gcol] =
                  (unsigned char)((gcol < N) ? f2e4m3(ov * ZSCALE) : 0u);
          }
        }
      }
    }
  }

  if (BCE) {
    rsum[tid] = bce;
    __syncthreads();
#pragma unroll
    for (int s = 128; s > 0; s >>= 1) {
      if (tid < s) rsum[tid] += rsum[tid + s];
      __syncthreads();
    }
    if (tid == 0) atomicAdd(loss_accum, rsum[0]);
  }
}

// ---------------------------------------------------------------------------
// MX-fp8 MFMA VQ argmin (mfma_scale 16x16x128, unit scales = 2x bf16 rate).
// r13 structure kept (256 thr, 4 waves x 64 rows, mf=4, 32-code tiles,
// 2x16KB LDS -> 2 blocks/CU).  Round-14 ILP fix: ks-outer / nf-inner with
// acc[2][4] -> 8 independent MFMA chains per wave (depth 4) instead of 4;
// r13 counters showed MFMA pipe issuing at ~1/3 rate (MfmaUtil 35% = 27us
// busy vs 7.3us of work at ubench rate) -- dependency-stalled, not
// capacity-bound.  a[] lives in AGPRs (r13: VGPR_Count 128, no spill), so
// +16 f32 acc is free.
// Grid = 64 rowgroups x 8 chunks = 512 blocks = 2/CU, chunk = bid&7.
// global_load_lds staging with 16B XOR swizzle (LDS[r][u] = G[r][u^(r&7)]).
// score = esqh - acc (esqh = 0.5*SQSCALE*||e||^2); ||z||^2 argmin-invariant.
// ---------------------------------------------------------------------------
__global__ __launch_bounds__(256, 1)
void vq_mfma_kernel(const unsigned char* __restrict__ zef,
                    const unsigned char* __restrict__ embf,
                    const float* __restrict__ esqh,
                    float* __restrict__ cand_val, int* __restrict__ cand_idx) {
  __shared__ __align__(16) unsigned char etile[2][32 * 512];

  const int tid  = threadIdx.x;
  const int w    = tid >> 6, lane = tid & 63;
  const int cq   = lane >> 4, cr = lane & 15;

  const int chunk    = blockIdx.x & 7;
  const int rowblock = blockIdx.x >> 3;    // 0..63
  const int rowBase  = rowblock * 256;
  const int codeBase = chunk * 1024;

  // A fragments: 64 rows/wave.  row = lane&15, per-lane 32 contiguous
  // k-bytes at cq*32 within each K=128 slice (layout verified rounds 5-13).
  i32x8 a[4][4];
  {
    const unsigned char* z0 =
        zef + (size_t)(rowBase + w * 64 + cr) * D_SZ + cq * 32;
#pragma unroll
    for (int mf = 0; mf < 4; ++mf)
#pragma unroll
      for (int ks = 0; ks < 4; ++ks)
        a[mf][ks] =
            *reinterpret_cast<const i32x8*>(z0 + mf * 16 * D_SZ + ks * 128);
  }

  float minv[4][4];
  int   mini[4][4];
#pragma unroll
  for (int mf = 0; mf < 4; ++mf)
#pragma unroll
    for (int r4 = 0; r4 < 4; ++r4) { minv[mf][r4] = FLT_MAX; mini[mf][r4] = 0; }

  // Staging: 32 rows x 512 B = 16 KB per buffer; 256 thr x 16 B x 4 passes.
  const int srow  = tid >> 5;              // 0..7; row&7 == srow (p*8 step)
  const int sunit = tid & 31;              // 16B unit within a 512B row
  const int soff  = (sunit ^ srow) << 4;
  auto stage = [&](int tt, int bb) {
#pragma unroll
    for (int p = 0; p < 4; ++p) {
      const int row = p * 8 + srow;
      const unsigned char* g =
          embf + (size_t)(codeBase + tt * 32 + row) * D_SZ + soff;
      __builtin_amdgcn_global_load_lds(
          (const __attribute__((address_space(1))) unsigned int*)g,
          (__attribute__((address_space(3))) unsigned int*)
              &etile[bb][(p * 8 + w * 2) * 512 + (lane << 4)],
          16, 0, 0);
    }
  };

  stage(0, 0);
  __syncthreads();

  const int swz = cr & 7;
  const char* lds0 = (const char*)etile[0];
  const char* lds1 = (const char*)etile[1];
  const float* esq_c = esqh + codeBase;

  for (int t = 0; t < 32; ++t) {
    const int bb = t & 1;
    if (t + 1 < 32) stage(t + 1, bb ^ 1);
    const char* buf = bb ? lds1 : lds0;
    const int tb = t * 32;

    // ks-outer / nf-inner: 8 independent accumulator chains (depth 4)
    f32x4 acc8[2][4] = {};
#pragma unroll
    for (int ks = 0; ks < 4; ++ks) {
      const int ub = (ks << 3) + (cq << 1);
#pragma unroll
      for (int nf = 0; nf < 2; ++nf) {
        const int rb = (nf * 16 + cr) * 512;
        const i32x4 lo =
            *reinterpret_cast<const i32x4*>(buf + rb + ((ub ^ swz) << 4));
        const i32x4 hi =
            *reinterpret_cast<const i32x4*>(buf + rb + (((ub + 1) ^ swz) << 4));
        const i32x8 bv = __builtin_shufflevector(lo, hi, 0, 1, 2, 3, 4, 5, 6, 7);
#pragma unroll
        for (int mf = 0; mf < 4; ++mf)
          acc8[nf][mf] = __builtin_amdgcn_mfma_scale_f32_16x16x128_f8f6f4(
              a[mf][ks], bv, acc8[nf][mf], 0, 0, 0, 0x7F, 0, 0x7F);
      }
    }

#pragma unroll
    for (int nf = 0; nf < 2; ++nf) {
      const int cl = tb + nf * 16 + cr;
      const float h = esq_c[cl];
      const int c = codeBase + cl;
#pragma unroll
      for (int mf = 0; mf < 4; ++mf)
#pragma unroll
        for (int r4 = 0; r4 < 4; ++r4) {
          const float s = h - acc8[nf][mf][r4];
          if (s < minv[mf][r4]) { minv[mf][r4] = s; mini[mf][r4] = c; }
        }
    }
    __syncthreads();
  }

  // cross-lane argmin over the 16 column-lanes, tie -> min idx
#pragma unroll
  for (int mf = 0; mf < 4; ++mf)
#pragma unroll
    for (int r4 = 0; r4 < 4; ++r4) {
      float v = minv[mf][r4];
      int   i = mini[mf][r4];
#pragma unroll
      for (int m = 1; m < 16; m <<= 1) {
        float ov = __shfl_xor(v, m, 64);
        int   oi = __shfl_xor(i, m, 64);
        if (ov < v || (ov == v && oi < i)) { v = ov; i = oi; }
      }
      if (cr == 0) {
        const int row = rowBase + w * 64 + mf * 16 + cq * 4 + r4;
        cand_val[(size_t)chunk * B_SZ + row] = v;
        cand_idx[(size_t)chunk * B_SZ + row] = i;
      }
    }
}

// ---------------------------------------------------------------------------
__global__ __launch_bounds__(256)
void vq_finalize_kernel(const float* __restrict__ cv, const int* __restrict__ ci,
                        int* __restrict__ idx) {
  const int r = blockIdx.x * 256 + threadIdx.x;
  float bv = cv[r];
  int   bi = ci[r];
#pragma unroll
  for (int c = 1; c < 8; ++c) {
    const float v = cv[(size_t)c * B_SZ + r];
    const int  i2 = ci[(size_t)c * B_SZ + r];
    if (v < bv || (v == bv && i2 < bi)) { bv = v; bi = i2; }
  }
  idx[r] = bi;
}

// ---------------------------------------------------------------------------
// sum((z_e - emb[idx])^2) -> accum[1], z_e read from bf16 zeb, emb exact fp32
// ---------------------------------------------------------------------------
__global__ __launch_bounds__(256)
void vqloss_kernel(const unsigned short* __restrict__ zeb,
                   const float* __restrict__ emb,
                   const int* __restrict__ idx, float* __restrict__ accum) {
  __shared__ float rsum[256];
  const int tid = threadIdx.x;
  const size_t stride = (size_t)gridDim.x * 256;
  const size_t total = (size_t)B_SZ * (D_SZ / 8);
  float s = 0.f;
  for (size_t e = (size_t)blockIdx.x * 256 + tid; e < total; e += stride) {
    const size_t b = e >> 6;
    const int   d8 = (int)(e & 63);
    bf16x8 z = *reinterpret_cast<const bf16x8*>(zeb + b * D_SZ + d8 * 8);
    const float* q = emb + (size_t)idx[b] * D_SZ + d8 * 8;
    const float4 q0 = *reinterpret_cast<const float4*>(q);
    const float4 q1 = *reinterpret_cast<const float4*>(q + 4);
    const float qa[8] = {q0.x, q0.y, q0.z, q0.w, q1.x, q1.y, q1.z, q1.w};
#pragma unroll
    for (int j = 0; j < 8; ++j) {
      const float d = bf2f((unsigned short)z[j]) - qa[j];
      s += d * d;
    }
  }
  rsum[tid] = s;
  __syncthreads();
#pragma unroll
  for (int st = 128; st > 0; st >>= 1) {
    if (tid < st) rsum[tid] += rsum[tid + st];
    __syncthreads();
  }
  if (tid == 0) atomicAdd(accum + 1, rsum[0]);
}

// ---------------------------------------------------------------------------
__global__ void finalize_kernel(const float* __restrict__ accum,
                                float* __restrict__ out) {
  const float rl = -accum[0] / ((float)B_SZ * (float)DIN);
  const float el = accum[1] / (float)B_SZ;
  out[(size_t)B_SZ * DIN + 0] = rl;
  out[(size_t)B_SZ * DIN + 1] = el;
  out[(size_t)B_SZ * DIN + 2] = el;
}

// ---------------------------------------------------------------------------
extern "C" void kernel_launch(void* const* d_in, const int* in_sizes, int n_in,
                              void* d_out, int out_size, void* d_ws,
                              size_t ws_size, hipStream_t stream) {
  const float* x   = (const float*)d_in[0];
  const float* W1  = (const float*)d_in[1];
  const float* b1  = (const float*)d_in[2];
  const float* W2  = (const float*)d_in[3];
  const float* b2  = (const float*)d_in[4];
  const float* W3  = (const float*)d_in[5];
  const float* b3  = (const float*)d_in[6];
  const float* W4  = (const float*)d_in[7];
  const float* b4  = (const float*)d_in[8];
  const float* emb = (const float*)d_in[9];
  float* out = (float*)d_out;

  // ---- workspace layout ----
  char* wsb = (char*)d_ws;
  auto alloc = [&](size_t bytes) {
    char* p = wsb;
    wsb += (bytes + 255) & ~(size_t)255;
    return p;
  };
  const size_t xb_bytes  = (size_t)B_SZ * DIN_P * 2;   // 26.2 MB
  const size_t zeb_bytes = (size_t)B_SZ * D_SZ * 2;    // 16.8 MB
  char* regionA = alloc(xb_bytes);  // xb; later zeb+embb (xb dead after gemm1)
  unsigned short* xb   = (unsigned short*)regionA;
  unsigned short* zeb  = (unsigned short*)regionA;
  unsigned short* embb = (unsigned short*)(regionA + zeb_bytes);
  char* regionB = alloc((size_t)B_SZ * H_P * 2);       // h1b, later h3b
  unsigned short* h1b = (unsigned short*)regionB;
  unsigned short* h3b = (unsigned short*)regionB;
  unsigned short* W1t = (unsigned short*)alloc((size_t)512 * DIN_P * 2);
  unsigned short* W2t = (unsigned short*)alloc((size_t)512 * H_P * 2);
  unsigned short* W3t = (unsigned short*)alloc((size_t)512 * D_SZ * 2);
  unsigned short* W4t = (unsigned short*)alloc((size_t)896 * H_P * 2);
  unsigned char* zef  = (unsigned char*)alloc((size_t)B_SZ * D_SZ);  // 8.4 MB
  unsigned char* embf = (unsigned char*)alloc((size_t)K_SZ * D_SZ);  // 4.2 MB
  float* esqh  = (float*)alloc((size_t)K_SZ * 4);
  float* accum = (float*)alloc(64);
  int*   idx   = (int*)alloc((size_t)B_SZ * 4);
  float* cand_val = (float*)alloc((size_t)8 * B_SZ * 4);
  int*   cand_idx = (int*)alloc((size_t)8 * B_SZ * 4);

  // 1) bf16 operand prep
  castpad_x_kernel<<<2048, 256, 0, stream>>>(x, xb);
  wtrans_kernel<<<dim3(25, 16), 256, 0, stream>>>(W1, W1t, DIN, H_SZ, DIN_P, 512);
  wtrans_kernel<<<dim3(13, 16), 256, 0, stream>>>(W2, W2t, H_SZ, D_SZ, H_P, 512);
  wtrans_kernel<<<dim3(16, 16), 256, 0, stream>>>(W3, W3t, D_SZ, H_SZ, D_SZ, 512);
  wtrans_kernel<<<dim3(13, 28), 256, 0, stream>>>(W4, W4t, H_SZ, DIN, H_P, 896);
  // 2) h1 = relu(x @ W1 + b1)
  mgemm_kernel<1, false, false, false, false>
      <<<dim3(4, B_SZ / 128), 256, 0, stream>>>(
      xb, W1t, b1, h1b, H_SZ, DIN_P, H_P, nullptr, nullptr, nullptr, nullptr);
  // 3) emb -> bf16 + fp8 + esqh + zero accum (regionA tail free now)
  embprep_kernel<<<K_SZ / 4, 256, 0, stream>>>(emb, embb, embf, esqh, accum);
  // 4) z_e = h1 @ W2 + b2  (bf16 zeb + fp8 zef)
  mgemm_kernel<0, false, false, false, true>
      <<<dim3(4, B_SZ / 128), 256, 0, stream>>>(
      h1b, W2t, b2, zeb, D_SZ, H_P, D_SZ, nullptr, nullptr, nullptr, zef);
  // 5) VQ argmin (MX fp8 MFMA)
  vq_mfma_kernel<<<512, 256, 0, stream>>>(zef, embf, esqh, cand_val, cand_idx);
  vq_finalize_kernel<<<B_SZ / 256, 256, 0, stream>>>(cand_val, cand_idx, idx);
  // 6) embed/commit loss
  vqloss_kernel<<<1024, 256, 0, stream>>>(zeb, emb, idx, accum);
  // 7) h3 = relu(emb[idx] @ W3 + b3)
  mgemm_kernel<1, true, false, false, false>
      <<<dim3(4, B_SZ / 128), 256, 0, stream>>>(
      embb, W3t, b3, h3b, H_SZ, D_SZ, H_P, idx, nullptr, nullptr, nullptr);
  // 8) x_reconst = sigmoid(h3 @ W4 + b4), fused fast BCE
  mgemm_kernel<2, false, true, true, false>
      <<<dim3(7, B_SZ / 128), 256, 0, stream>>>(
      h3b, W4t, b4, out, DIN, H_P, DIN, nullptr, x, accum, nullptr);
  // 9) scalars
  finalize_kernel<<<1, 1, 0, stream>>>(accum, out);
}

// Round 15
// 256.686 us; speedup vs baseline: 1.0587x; 1.0587x over previous
//
#include <hip/hip_runtime.h>
#include <cfloat>
#include <cstddef>

#define B_SZ 16384
#define DIN  784
#define H_SZ 400
#define D_SZ 512
#define K_SZ 8192

#define DIN_P 800   // 784 padded to 25*32
#define H_P   416   // 400 padded to 13*32

#define ZSCALE 64.f
#define ESCALE 256.f
#define SQSCALE (ZSCALE * ESCALE)
#define SBIAS  16384.f   // makes all VQ scores positive (u32-sortable)

typedef short bf16x8 __attribute__((ext_vector_type(8)));
typedef float f32x4  __attribute__((ext_vector_type(4)));
typedef int   i32x4  __attribute__((ext_vector_type(4)));
typedef int   i32x8  __attribute__((ext_vector_type(8)));

__device__ __forceinline__ unsigned short f2bf(float f) {
  unsigned u = __float_as_uint(f);
  unsigned r = (u + 0x7FFFu + ((u >> 16) & 1u)) >> 16;
  return (unsigned short)r;
}
__device__ __forceinline__ float bf2f(unsigned short h) {
  return __uint_as_float(((unsigned)h) << 16);
}
// fp32 -> OCP e4m3fn (RNE in normal range, RN in subnormal, clamp to 448)
__device__ __forceinline__ unsigned f2e4m3(float f) {
  unsigned u = __float_as_uint(f);
  const unsigned sign = (u >> 24) & 0x80u;
  const float af = __uint_as_float(u & 0x7FFFFFFFu);
  if (af >= 448.f) return sign | 0x7Eu;
  if (af < 0.015625f) {                  // subnormal, unit 2^-9
    const int m = (int)(af * 512.f + 0.5f);
    return sign | (unsigned)m;
  }
  u = (u & 0x7FFFFFFFu) + 0x7FFFFu + ((u >> 20) & 1u);
  const unsigned e8 = (u >> 23) - 120u;  // -127+7
  if (e8 >= 16u) return sign | 0x7Eu;
  return sign | (e8 << 3) | ((u >> 20) & 7u);
}

// ---------------------------------------------------------------------------
// Fused emb prep: bf16 copy + fp8*ESCALE copy + esqh' = 0.5*SQSCALE*||e||^2
// + SBIAS (pre-biased so scores are positive -> u32-sortable), + zero accum.
// ---------------------------------------------------------------------------
__global__ __launch_bounds__(256)
void embprep_kernel(const float* __restrict__ emb,
                    unsigned short* __restrict__ embb,
                    unsigned char* __restrict__ embf,
                    float* __restrict__ esqh, float* __restrict__ accum) {
  if (blockIdx.x == 0 && threadIdx.x == 0) { accum[0] = 0.f; accum[1] = 0.f; }
  const int row  = blockIdx.x * 4 + (threadIdx.x >> 6);
  const int lane = threadIdx.x & 63;
  const float* p = emb + (size_t)row * D_SZ + lane * 8;
  const float4 v0 = *reinterpret_cast<const float4*>(p);
  const float4 v1 = *reinterpret_cast<const float4*>(p + 4);

  ushort4 h0, h1;
  h0.x = f2bf(v0.x); h0.y = f2bf(v0.y); h0.z = f2bf(v0.z); h0.w = f2bf(v0.w);
  h1.x = f2bf(v1.x); h1.y = f2bf(v1.y); h1.z = f2bf(v1.z); h1.w = f2bf(v1.w);
  reinterpret_cast<ushort4*>(embb + (size_t)row * D_SZ + lane * 8)[0] = h0;
  reinterpret_cast<ushort4*>(embb + (size_t)row * D_SZ + lane * 8 + 4)[0] = h1;

  uint2 q;
  q.x = f2e4m3(v0.x * ESCALE) | (f2e4m3(v0.y * ESCALE) << 8) |
        (f2e4m3(v0.z * ESCALE) << 16) | (f2e4m3(v0.w * ESCALE) << 24);
  q.y = f2e4m3(v1.x * ESCALE) | (f2e4m3(v1.y * ESCALE) << 8) |
        (f2e4m3(v1.z * ESCALE) << 16) | (f2e4m3(v1.w * ESCALE) << 24);
  *reinterpret_cast<uint2*>(embf + (size_t)row * D_SZ + lane * 8) = q;

  float s = v0.x * v0.x + v0.y * v0.y + v0.z * v0.z + v0.w * v0.w +
            v1.x * v1.x + v1.y * v1.y + v1.z * v1.z + v1.w * v1.w;
#pragma unroll
  for (int off = 32; off > 0; off >>= 1) s += __shfl_down(s, off);
  if (lane == 0) esqh[row] = 0.5f * SQSCALE * s + SBIAS;
}

// ---------------------------------------------------------------------------
// x [16384][784] fp32 -> xb [16384][800] bf16, zero-padded cols 784..799
// ---------------------------------------------------------------------------
__global__ __launch_bounds__(256)
void castpad_x_kernel(const float* __restrict__ x, unsigned short* __restrict__ xb) {
  int u = blockIdx.x * 256 + threadIdx.x;
  const int total = B_SZ * 200;
  const int stride = gridDim.x * 256;
  for (; u < total; u += stride) {
    const int row = u / 200, c4 = u - row * 200;
    ushort4 o = make_ushort4(0, 0, 0, 0);
    if (c4 < 196) {
      float4 v = *reinterpret_cast<const float4*>(x + (size_t)row * DIN + c4 * 4);
      o.x = f2bf(v.x); o.y = f2bf(v.y); o.z = f2bf(v.z); o.w = f2bf(v.w);
    }
    *reinterpret_cast<ushort4*>(xb + (size_t)row * DIN_P + c4 * 4) = o;
  }
}

// ---------------------------------------------------------------------------
// W [K][N] fp32 -> Wt [Npad][Kpad] bf16, zero-padded, LDS-tiled transpose.
// ---------------------------------------------------------------------------
__global__ __launch_bounds__(256)
void wtrans_kernel(const float* __restrict__ W, unsigned short* __restrict__ Wt,
                   int K, int N, int Kpad, int Npad) {
  __shared__ float t[32][33];
  const int tx = threadIdx.x & 31, ty = threadIdx.x >> 5;
  const int k0 = blockIdx.x * 32, n0 = blockIdx.y * 32;
#pragma unroll
  for (int s = 0; s < 4; ++s) {
    const int k = k0 + ty + s * 8, n = n0 + tx;
    t[ty + s * 8][tx] = (k < K && n < N) ? W[(size_t)k * N + n] : 0.f;
  }
  __syncthreads();
#pragma unroll
  for (int s = 0; s < 4; ++s) {
    const int n = n0 + ty + s * 8, k = k0 + tx;
    if (n < Npad && k < Kpad)
      Wt[(size_t)n * Kpad + k] = f2bf(t[tx][ty + s * 8]);
  }
}

// ---------------------------------------------------------------------------
// MFMA GEMM: C = act(A @ Bt^T + bias).  BM=BN=128, BK=32, 4 waves (2x2),
// acc 4x4 of 16x16x32 bf16 fragments, double-buffered global_load_lds.
// ACT: 0=none 1=relu 2=sigmoid (fast).  BCE fused (x-1)*v - ln(1+e^-v).
// XCD-chunked block swizzle: bid=(d%8)*(nwg/8)+d/8.
// ---------------------------------------------------------------------------
template <int ACT, bool GATHER, bool BCE, bool OUTF32, bool FP8OUT>
__global__ __launch_bounds__(256, 3)
void mgemm_kernel(const unsigned short* __restrict__ A,
                  const unsigned short* __restrict__ Bt,
                  const float* __restrict__ bias, void* __restrict__ C,
                  int N, int Kpad, int NpadOut,
                  const int* __restrict__ gidx,
                  const float* __restrict__ xg, float* __restrict__ loss_accum,
                  unsigned char* __restrict__ C8) {
  __shared__ __align__(16) unsigned short As[2][128 * 32];
  __shared__ __align__(16) unsigned short Bs[2][128 * 32];
  __shared__ int   sidx[128];
  __shared__ float rsum[256];

  const int tid  = threadIdx.x;
  const int w    = tid >> 6, lane = tid & 63;
  const int wr   = w >> 1, wc = w & 1;

  const int nwg = gridDim.x * gridDim.y;
  int bid = blockIdx.y * gridDim.x + blockIdx.x;
  bid = (bid & 7) * (nwg >> 3) + (bid >> 3);
  const int bx = bid % gridDim.x, by = bid / gridDim.x;
  const int rowBase = by * 128, colBase = bx * 128;

  if (GATHER) {
    if (tid < 128) sidx[tid] = gidx[rowBase + tid];
    __syncthreads();
  }

  const int srow  = lane >> 2;
  const int sunit = lane & 3;

  auto stageA = [&](int kt, int bb) {
#pragma unroll
    for (int c = 0; c < 2; ++c) {
      const int rowq = (c * 4 + w) * 16 + srow;
      const long arow = GATHER ? (long)sidx[rowq] : (long)(rowBase + rowq);
      const unsigned short* g = A + (size_t)arow * Kpad + kt * 32 + sunit * 8;
      __builtin_amdgcn_global_load_lds(
          (const __attribute__((address_space(1))) unsigned int*)g,
          (__attribute__((address_space(3))) unsigned int*)
              &As[bb][(((c * 4 + w) * 64) + lane) * 8],
          16, 0, 0);
    }
  };
  auto stageB = [&](int kt, int bb) {
#pragma unroll
    for (int c = 0; c < 2; ++c) {
      const int rowq = (c * 4 + w) * 16 + srow;
      const unsigned short* g =
          Bt + (size_t)(colBase + rowq) * Kpad + kt * 32 + sunit * 8;
      __builtin_amdgcn_global_load_lds(
          (const __attribute__((address_space(1))) unsigned int*)g,
          (__attribute__((address_space(3))) unsigned int*)
              &Bs[bb][(((c * 4 + w) * 64) + lane) * 8],
          16, 0, 0);
    }
  };

  f32x4 acc[4][4] = {};
  stageA(0, 0); stageB(0, 0);
  const int nk = Kpad >> 5;
  const int lr = lane >> 4, lc = lane & 15;

  for (int kt = 0; kt < nk; ++kt) {
    const int bb = kt & 1;
    __syncthreads();
    if (kt + 1 < nk) { stageA(kt + 1, bb ^ 1); stageB(kt + 1, bb ^ 1); }
    bf16x8 a[4], b[4];
#pragma unroll
    for (int f = 0; f < 4; ++f) {
      const int ra = wr * 64 + f * 16 + lc;
      a[f] = *reinterpret_cast<const bf16x8*>(&As[bb][ra * 32 + lr * 8]);
      const int rb = wc * 64 + f * 16 + lc;
      b[f] = *reinterpret_cast<const bf16x8*>(&Bs[bb][rb * 32 + lr * 8]);
    }
#pragma unroll
    for (int i = 0; i < 4; ++i)
#pragma unroll
      for (int j = 0; j < 4; ++j)
        acc[i][j] =
            __builtin_amdgcn_mfma_f32_16x16x32_bf16(a[i], b[j], acc[i][j], 0, 0, 0);
  }

  float bce = 0.f;
#pragma unroll
  for (int j = 0; j < 4; ++j) {
    const int gcol = colBase + wc * 64 + j * 16 + lc;
    const float bj = (gcol < N) ? bias[gcol] : 0.f;
#pragma unroll
    for (int i = 0; i < 4; ++i) {
      const int growb = rowBase + wr * 64 + i * 16 + lr * 4;
#pragma unroll
      for (int r = 0; r < 4; ++r) {
        float v = acc[i][j][r] + bj;
        if (ACT == 1) v = fmaxf(v, 0.f);
        float e2 = 0.f, ov = v;
        if (ACT == 2) {
          e2 = __builtin_amdgcn_exp2f(v * -1.442695041f);   // exp(-v)
          ov = __builtin_amdgcn_rcpf(1.f + e2);             // sigmoid
        }
        const int grow = growb + r;
        if (OUTF32) {
          if (gcol < N) {
            ((float*)C)[(size_t)grow * N + gcol] = ov;
            if (BCE) {
              const float L =
                  0.69314718056f * __builtin_amdgcn_logf(1.f + e2);
              const float xv = xg[(size_t)grow * N + gcol];
              bce += (xv - 1.f) * v - L;
            }
          }
        } else {
          if (gcol < NpadOut) {
            const unsigned short hv = (gcol < N) ? f2bf(ov) : (unsigned short)0;
            ((unsigned short*)C)[(size_t)grow * NpadOut + gcol] = hv;
            if (FP8OUT)
              C8[(size_t)grow * NpadOut + gcol] =
                  (unsigned char)((gcol < N) ? f2e4m3(ov * ZSCALE) : 0u);
          }
        }
      }
    }
  }

  if (BCE) {
    rsum[tid] = bce;
    __syncthreads();
#pragma unroll
    for (int s = 128; s > 0; s >>= 1) {
      if (tid < s) rsum[tid] += rsum[tid + s];
      __syncthreads();
    }
    if (tid == 0) atomicAdd(loss_accum, rsum[0]);
  }
}

// ---------------------------------------------------------------------------
// MX-fp8 MFMA VQ argmin.  r13 structure (256 thr, 4 waves x 64 rows, mf=4,
// nf-outer acc4, 32-code tiles, 2x16KB LDS -> 2 blocks/CU; per-wave unified
// regs must stay <= 256 -- r14's +16 acc regs broke co-residency).
// Round-15: packed-u32 argmin.  esqh pre-biased +SBIAS makes every score
// positive -> IEEE bits are order-preserving; key = (bits & ~8191) | code.
// Score update = sub + and_or + min_u32 (3 VALU vs 4) and mini[] dies
// (-16 arch regs).  Masked mantissa step (~16 scaled units) << typical
// top-2 gap (~82); collapsed near-ties resolve to min idx = argmin rule.
// Grid = 64 rowgroups x 8 chunks = 512 blocks = 2/CU, chunk = bid&7.
// global_load_lds staging with 16B XOR swizzle (LDS[r][u] = G[r][u^(r&7)]).
// ---------------------------------------------------------------------------
__global__ __launch_bounds__(256, 1)
void vq_mfma_kernel(const unsigned char* __restrict__ zef,
                    const unsigned char* __restrict__ embf,
                    const float* __restrict__ esqh,
                    unsigned* __restrict__ cand_key) {
  __shared__ __align__(16) unsigned char etile[2][32 * 512];

  const int tid  = threadIdx.x;
  const int w    = tid >> 6, lane = tid & 63;
  const int cq   = lane >> 4, cr = lane & 15;

  const int chunk    = blockIdx.x & 7;
  const int rowblock = blockIdx.x >> 3;    // 0..63
  const int rowBase  = rowblock * 256;
  const int codeBase = chunk * 1024;

  // A fragments: 64 rows/wave (layout verified rounds 5-14)
  i32x8 a[4][4];
  {
    const unsigned char* z0 =
        zef + (size_t)(rowBase + w * 64 + cr) * D_SZ + cq * 32;
#pragma unroll
    for (int mf = 0; mf < 4; ++mf)
#pragma unroll
      for (int ks = 0; ks < 4; ++ks)
        a[mf][ks] =
            *reinterpret_cast<const i32x8*>(z0 + mf * 16 * D_SZ + ks * 128);
  }

  unsigned minu[4][4];
#pragma unroll
  for (int mf = 0; mf < 4; ++mf)
#pragma unroll
    for (int r4 = 0; r4 < 4; ++r4) minu[mf][r4] = 0xFFFFFFFFu;

  // Staging: 32 rows x 512 B = 16 KB per buffer; 256 thr x 16 B x 4 passes.
  const int srow  = tid >> 5;              // 0..7; row&7 == srow (p*8 step)
  const int sunit = tid & 31;              // 16B unit within a 512B row
  const int soff  = (sunit ^ srow) << 4;
  auto stage = [&](int tt, int bb) {
#pragma unroll
    for (int p = 0; p < 4; ++p) {
      const int row = p * 8 + srow;
      const unsigned char* g =
          embf + (size_t)(codeBase + tt * 32 + row) * D_SZ + soff;
      __builtin_amdgcn_global_load_lds(
          (const __attribute__((address_space(1))) unsigned int*)g,
          (__attribute__((address_space(3))) unsigned int*)
              &etile[bb][(p * 8 + w * 2) * 512 + (lane << 4)],
          16, 0, 0);
    }
  };

  stage(0, 0);
  __syncthreads();

  const int swz = cr & 7;
  const char* lds0 = (const char*)etile[0];
  const char* lds1 = (const char*)etile[1];
  const float* esq_c = esqh + codeBase;

  for (int t = 0; t < 32; ++t) {
    const int bb = t & 1;
    if (t + 1 < 32) stage(t + 1, bb ^ 1);
    const char* buf = bb ? lds1 : lds0;
    const int tb = t * 32;

#pragma unroll
    for (int nf = 0; nf < 2; ++nf) {
      const int rb = (nf * 16 + cr) * 512;
      f32x4 acc4[4] = {};
#pragma unroll
      for (int ks = 0; ks < 4; ++ks) {
        const int ub = (ks << 3) + (cq << 1);
        const i32x4 lo =
            *reinterpret_cast<const i32x4*>(buf + rb + ((ub ^ swz) << 4));
        const i32x4 hi =
            *reinterpret_cast<const i32x4*>(buf + rb + (((ub + 1) ^ swz) << 4));
        const i32x8 bv = __builtin_shufflevector(lo, hi, 0, 1, 2, 3, 4, 5, 6, 7);
#pragma unroll
        for (int mf = 0; mf < 4; ++mf)
          acc4[mf] = __builtin_amdgcn_mfma_scale_f32_16x16x128_f8f6f4(
              a[mf][ks], bv, acc4[mf], 0, 0, 0, 0x7F, 0, 0x7F);
      }
      const int cl = tb + nf * 16 + cr;
      const float h = esq_c[cl];               // includes +SBIAS
      const unsigned c = (unsigned)(codeBase + cl);
#pragma unroll
      for (int mf = 0; mf < 4; ++mf)
#pragma unroll
        for (int r4 = 0; r4 < 4; ++r4) {
          const float s = h - acc4[mf][r4];    // > 0 by SBIAS
          const unsigned key = (__float_as_uint(s) & 0xFFFFE000u) | c;
          minu[mf][r4] = min(minu[mf][r4], key);
        }
    }
    __syncthreads();
  }

  // cross-lane u32-min over the 16 column-lanes (tie -> min idx automatic)
#pragma unroll
  for (int mf = 0; mf < 4; ++mf)
#pragma unroll
    for (int r4 = 0; r4 < 4; ++r4) {
      unsigned k = minu[mf][r4];
#pragma unroll
      for (int m = 1; m < 16; m <<= 1) {
        const unsigned ok =
            (unsigned)__shfl_xor((int)k, m, 64);
        k = min(k, ok);
      }
      if (cr == 0) {
        const int row = rowBase + w * 64 + mf * 16 + cq * 4 + r4;
        cand_key[(size_t)chunk * B_SZ + row] = k;
      }
    }
}

// ---------------------------------------------------------------------------
__global__ __launch_bounds__(256)
void vq_finalize_kernel(const unsigned* __restrict__ ck, int* __restrict__ idx) {
  const int r = blockIdx.x * 256 + threadIdx.x;
  unsigned k = ck[r];
#pragma unroll
  for (int c = 1; c < 8; ++c) k = min(k, ck[(size_t)c * B_SZ + r]);
  idx[r] = (int)(k & 8191u);
}

// ---------------------------------------------------------------------------
// sum((z_e - emb[idx])^2) -> accum[1], z_e read from bf16 zeb, emb exact fp32
// ---------------------------------------------------------------------------
__global__ __launch_bounds__(256)
void vqloss_kernel(const unsigned short* __restrict__ zeb,
                   const float* __restrict__ emb,
                   const int* __restrict__ idx, float* __restrict__ accum) {
  __shared__ float rsum[256];
  const int tid = threadIdx.x;
  const size_t stride = (size_t)gridDim.x * 256;
  const size_t total = (size_t)B_SZ * (D_SZ / 8);
  float s = 0.f;
  for (size_t e = (size_t)blockIdx.x * 256 + tid; e < total; e += stride) {
    const size_t b = e >> 6;
    const int   d8 = (int)(e & 63);
    bf16x8 z = *reinterpret_cast<const bf16x8*>(zeb + b * D_SZ + d8 * 8);
    const float* q = emb + (size_t)idx[b] * D_SZ + d8 * 8;
    const float4 q0 = *reinterpret_cast<const float4*>(q);
    const float4 q1 = *reinterpret_cast<const float4*>(q + 4);
    const float qa[8] = {q0.x, q0.y, q0.z, q0.w, q1.x, q1.y, q1.z, q1.w};
#pragma unroll
    for (int j = 0; j < 8; ++j) {
      const float d = bf2f((unsigned short)z[j]) - qa[j];
      s += d * d;
    }
  }
  rsum[tid] = s;
  __syncthreads();
#pragma unroll
  for (int st = 128; st > 0; st >>= 1) {
    if (tid < st) rsum[tid] += rsum[tid + st];
    __syncthreads();
  }
  if (tid == 0) atomicAdd(accum + 1, rsum[0]);
}

// ---------------------------------------------------------------------------
__global__ void finalize_kernel(const float* __restrict__ accum,
                                float* __restrict__ out) {
  const float rl = -accum[0] / ((float)B_SZ * (float)DIN);
  const float el = accum[1] / (float)B_SZ;
  out[(size_t)B_SZ * DIN + 0] = rl;
  out[(size_t)B_SZ * DIN + 1] = el;
  out[(size_t)B_SZ * DIN + 2] = el;
}

// ---------------------------------------------------------------------------
extern "C" void kernel_launch(void* const* d_in, const int* in_sizes, int n_in,
                              void* d_out, int out_size, void* d_ws,
                              size_t ws_size, hipStream_t stream) {
  const float* x   = (const float*)d_in[0];
  const float* W1  = (const float*)d_in[1];
  const float* b1  = (const float*)d_in[2];
  const float* W2  = (const float*)d_in[3];
  const float* b2  = (const float*)d_in[4];
  const float* W3  = (const float*)d_in[5];
  const float* b3  = (const float*)d_in[6];
  const float* W4  = (const float*)d_in[7];
  const float* b4  = (const float*)d_in[8];
  const float* emb = (const float*)d_in[9];
  float* out = (float*)d_out;

  // ---- workspace layout ----
  char* wsb = (char*)d_ws;
  auto alloc = [&](size_t bytes) {
    char* p = wsb;
    wsb += (bytes + 255) & ~(size_t)255;
    return p;
  };
  const size_t xb_bytes  = (size_t)B_SZ * DIN_P * 2;   // 26.2 MB
  const size_t zeb_bytes = (size_t)B_SZ * D_SZ * 2;    // 16.8 MB
  char* regionA = alloc(xb_bytes);  // xb; later zeb+embb (xb dead after gemm1)
  unsigned short* xb   = (unsigned short*)regionA;
  unsigned short* zeb  = (unsigned short*)regionA;
  unsigned short* embb = (unsigned short*)(regionA + zeb_bytes);
  char* regionB = alloc((size_t)B_SZ * H_P * 2);       // h1b, later h3b
  unsigned short* h1b = (unsigned short*)regionB;
  unsigned short* h3b = (unsigned short*)regionB;
  unsigned short* W1t = (unsigned short*)alloc((size_t)512 * DIN_P * 2);
  unsigned short* W2t = (unsigned short*)alloc((size_t)512 * H_P * 2);
  unsigned short* W3t = (unsigned short*)alloc((size_t)512 * D_SZ * 2);
  unsigned short* W4t = (unsigned short*)alloc((size_t)896 * H_P * 2);
  unsigned char* zef  = (unsigned char*)alloc((size_t)B_SZ * D_SZ);  // 8.4 MB
  unsigned char* embf = (unsigned char*)alloc((size_t)K_SZ * D_SZ);  // 4.2 MB
  float* esqh  = (float*)alloc((size_t)K_SZ * 4);
  float* accum = (float*)alloc(64);
  int*   idx   = (int*)alloc((size_t)B_SZ * 4);
  unsigned* cand_key = (unsigned*)alloc((size_t)8 * B_SZ * 4);

  // 1) bf16 operand prep
  castpad_x_kernel<<<2048, 256, 0, stream>>>(x, xb);
  wtrans_kernel<<<dim3(25, 16), 256, 0, stream>>>(W1, W1t, DIN, H_SZ, DIN_P, 512);
  wtrans_kernel<<<dim3(13, 16), 256, 0, stream>>>(W2, W2t, H_SZ, D_SZ, H_P, 512);
  wtrans_kernel<<<dim3(16, 16), 256, 0, stream>>>(W3, W3t, D_SZ, H_SZ, D_SZ, 512);
  wtrans_kernel<<<dim3(13, 28), 256, 0, stream>>>(W4, W4t, H_SZ, DIN, H_P, 896);
  // 2) h1 = relu(x @ W1 + b1)
  mgemm_kernel<1, false, false, false, false>
      <<<dim3(4, B_SZ / 128), 256, 0, stream>>>(
      xb, W1t, b1, h1b, H_SZ, DIN_P, H_P, nullptr, nullptr, nullptr, nullptr);
  // 3) emb -> bf16 + fp8 + esqh(+SBIAS) + zero accum
  embprep_kernel<<<K_SZ / 4, 256, 0, stream>>>(emb, embb, embf, esqh, accum);
  // 4) z_e = h1 @ W2 + b2  (bf16 zeb + fp8 zef)
  mgemm_kernel<0, false, false, false, true>
      <<<dim3(4, B_SZ / 128), 256, 0, stream>>>(
      h1b, W2t, b2, zeb, D_SZ, H_P, D_SZ, nullptr, nullptr, nullptr, zef);
  // 5) VQ argmin (MX fp8 MFMA, packed-u32 keys)
  vq_mfma_kernel<<<512, 256, 0, stream>>>(zef, embf, esqh, cand_key);
  vq_finalize_kernel<<<B_SZ / 256, 256, 0, stream>>>(cand_key, idx);
  // 6) embed/commit loss
  vqloss_kernel<<<1024, 256, 0, stream>>>(zeb, emb, idx, accum);
  // 7) h3 = relu(emb[idx] @ W3 + b3)
  mgemm_kernel<1, true, false, false, false>
      <<<dim3(4, B_SZ / 128), 256, 0, stream>>>(
      embb, W3t, b3, h3b, H_SZ, D_SZ, H_P, idx, nullptr, nullptr, nullptr);
  // 8) x_reconst = sigmoid(h3 @ W4 + b4), fused fast BCE
  mgemm_kernel<2, false, true, true, false>
      <<<dim3(7, B_SZ / 128), 256, 0, stream>>>(
      h3b, W4t, b4, out, DIN, H_P, DIN, nullptr, x, accum, nullptr);
  // 9) scalars
  finalize_kernel<<<1, 1, 0, stream>>>(accum, out);
}

// Round 16
// 236.513 us; speedup vs baseline: 1.1490x; 1.0853x over previous
//
#include <hip/hip_runtime.h>
#include <cfloat>
#include <cstddef>

#define B_SZ 16384
#define DIN  784
#define H_SZ 400
#define D_SZ 512
#define K_SZ 8192

#define DIN_P 800   // 784 padded to 25*32
#define H_P   416   // 400 padded to 13*32

#define ZSCALE 64.f
#define ESCALE 256.f
#define SQSCALE (ZSCALE * ESCALE)

typedef short bf16x8 __attribute__((ext_vector_type(8)));
typedef float f32x4  __attribute__((ext_vector_type(4)));
typedef int   i32x4  __attribute__((ext_vector_type(4)));
typedef int   i32x8  __attribute__((ext_vector_type(8)));

__device__ __forceinline__ unsigned short f2bf(float f) {
  unsigned u = __float_as_uint(f);
  unsigned r = (u + 0x7FFFu + ((u >> 16) & 1u)) >> 16;
  return (unsigned short)r;
}
__device__ __forceinline__ float bf2f(unsigned short h) {
  return __uint_as_float(((unsigned)h) << 16);
}
// fp32 -> OCP e4m3fn (RNE in normal range, RN in subnormal, clamp to 448)
__device__ __forceinline__ unsigned f2e4m3(float f) {
  unsigned u = __float_as_uint(f);
  const unsigned sign = (u >> 24) & 0x80u;
  const float af = __uint_as_float(u & 0x7FFFFFFFu);
  if (af >= 448.f) return sign | 0x7Eu;
  if (af < 0.015625f) {                  // subnormal, unit 2^-9
    const int m = (int)(af * 512.f + 0.5f);
    return sign | (unsigned)m;
  }
  u = (u & 0x7FFFFFFFu) + 0x7FFFFu + ((u >> 20) & 1u);
  const unsigned e8 = (u >> 23) - 120u;  // -127+7
  if (e8 >= 16u) return sign | 0x7Eu;
  return sign | (e8 << 3) | ((u >> 20) & 7u);
}

// ---------------------------------------------------------------------------
// Fused emb prep: one pass over emb producing bf16 copy (decode gather),
// fp8*ESCALE copy (VQ scan), esqh = 0.5*SQSCALE*||e||^2, + zero accumulators.
// One wave per codebook row.  (r13 configuration, verified 244.8us total.)
// ---------------------------------------------------------------------------
__global__ __launch_bounds__(256)
void embprep_kernel(const float* __restrict__ emb,
                    unsigned short* __restrict__ embb,
                    unsigned char* __restrict__ embf,
                    float* __restrict__ esqh, float* __restrict__ accum) {
  if (blockIdx.x == 0 && threadIdx.x == 0) { accum[0] = 0.f; accum[1] = 0.f; }
  const int row  = blockIdx.x * 4 + (threadIdx.x >> 6);
  const int lane = threadIdx.x & 63;
  const float* p = emb + (size_t)row * D_SZ + lane * 8;
  const float4 v0 = *reinterpret_cast<const float4*>(p);
  const float4 v1 = *reinterpret_cast<const float4*>(p + 4);

  ushort4 h0, h1;
  h0.x = f2bf(v0.x); h0.y = f2bf(v0.y); h0.z = f2bf(v0.z); h0.w = f2bf(v0.w);
  h1.x = f2bf(v1.x); h1.y = f2bf(v1.y); h1.z = f2bf(v1.z); h1.w = f2bf(v1.w);
  reinterpret_cast<ushort4*>(embb + (size_t)row * D_SZ + lane * 8)[0] = h0;
  reinterpret_cast<ushort4*>(embb + (size_t)row * D_SZ + lane * 8 + 4)[0] = h1;

  uint2 q;
  q.x = f2e4m3(v0.x * ESCALE) | (f2e4m3(v0.y * ESCALE) << 8) |
        (f2e4m3(v0.z * ESCALE) << 16) | (f2e4m3(v0.w * ESCALE) << 24);
  q.y = f2e4m3(v1.x * ESCALE) | (f2e4m3(v1.y * ESCALE) << 8) |
        (f2e4m3(v1.z * ESCALE) << 16) | (f2e4m3(v1.w * ESCALE) << 24);
  *reinterpret_cast<uint2*>(embf + (size_t)row * D_SZ + lane * 8) = q;

  float s = v0.x * v0.x + v0.y * v0.y + v0.z * v0.z + v0.w * v0.w +
            v1.x * v1.x + v1.y * v1.y + v1.z * v1.z + v1.w * v1.w;
#pragma unroll
  for (int off = 32; off > 0; off >>= 1) s += __shfl_down(s, off);
  if (lane == 0) esqh[row] = 0.5f * SQSCALE * s;
}

// ---------------------------------------------------------------------------
// x [16384][784] fp32 -> xb [16384][800] bf16, zero-padded cols 784..799
// ---------------------------------------------------------------------------
__global__ __launch_bounds__(256)
void castpad_x_kernel(const float* __restrict__ x, unsigned short* __restrict__ xb) {
  int u = blockIdx.x * 256 + threadIdx.x;
  const int total = B_SZ * 200;
  const int stride = gridDim.x * 256;
  for (; u < total; u += stride) {
    const int row = u / 200, c4 = u - row * 200;
    ushort4 o = make_ushort4(0, 0, 0, 0);
    if (c4 < 196) {
      float4 v = *reinterpret_cast<const float4*>(x + (size_t)row * DIN + c4 * 4);
      o.x = f2bf(v.x); o.y = f2bf(v.y); o.z = f2bf(v.z); o.w = f2bf(v.w);
    }
    *reinterpret_cast<ushort4*>(xb + (size_t)row * DIN_P + c4 * 4) = o;
  }
}

// ---------------------------------------------------------------------------
// Batched weight transpose: all 4 W [K][N] fp32 -> Wt [Npad][Kpad] bf16 in
// ONE launch (saves 3 dispatch overheads).  Flat grid of 32x32 tiles; each
// block walks the 4-entry descriptor table to find its weight.
// ---------------------------------------------------------------------------
struct WtransArgs {
  const float* W[4];
  unsigned short* Wt[4];
  int K[4], N[4], Kpad[4], Npad[4], gx[4], off[5];
};

__global__ __launch_bounds__(256)
void wtrans4_kernel(WtransArgs args) {
  __shared__ float t[32][33];
  const int bid = blockIdx.x;
  int i = 0;
#pragma unroll
  for (int j = 1; j < 4; ++j) i += (bid >= args.off[j]);
  const int local = bid - args.off[i];
  const int k0 = (local % args.gx[i]) * 32;
  const int n0 = (local / args.gx[i]) * 32;
  const float* W = args.W[i];
  unsigned short* Wt = args.Wt[i];
  const int K = args.K[i], N = args.N[i];
  const int Kpad = args.Kpad[i], Npad = args.Npad[i];

  const int tx = threadIdx.x & 31, ty = threadIdx.x >> 5;
#pragma unroll
  for (int s = 0; s < 4; ++s) {
    const int k = k0 + ty + s * 8, n = n0 + tx;
    t[ty + s * 8][tx] = (k < K && n < N) ? W[(size_t)k * N + n] : 0.f;
  }
  __syncthreads();
#pragma unroll
  for (int s = 0; s < 4; ++s) {
    const int n = n0 + ty + s * 8, k = k0 + tx;
    if (n < Npad && k < Kpad)
      Wt[(size_t)n * Kpad + k] = f2bf(t[tx][ty + s * 8]);
  }
}

// ---------------------------------------------------------------------------
// MFMA GEMM: C = act(A @ Bt^T + bias).  BM=BN=128, BK=32, 4 waves (2x2),
// acc 4x4 of 16x16x32 bf16 fragments, double-buffered global_load_lds.
// ACT: 0=none 1=relu 2=sigmoid (fast).  BCE fused (x-1)*v - ln(1+e^-v).
// XCD-chunked block swizzle: bid=(d%8)*(nwg/8)+d/8.
// ---------------------------------------------------------------------------
template <int ACT, bool GATHER, bool BCE, bool OUTF32, bool FP8OUT>
__global__ __launch_bounds__(256, 3)
void mgemm_kernel(const unsigned short* __restrict__ A,
                  const unsigned short* __restrict__ Bt,
                  const float* __restrict__ bias, void* __restrict__ C,
                  int N, int Kpad, int NpadOut,
                  const int* __restrict__ gidx,
                  const float* __restrict__ xg, float* __restrict__ loss_accum,
                  unsigned char* __restrict__ C8) {
  __shared__ __align__(16) unsigned short As[2][128 * 32];
  __shared__ __align__(16) unsigned short Bs[2][128 * 32];
  __shared__ int   sidx[128];
  __shared__ float rsum[256];

  const int tid  = threadIdx.x;
  const int w    = tid >> 6, lane = tid & 63;
  const int wr   = w >> 1, wc = w & 1;

  const int nwg = gridDim.x * gridDim.y;
  int bid = blockIdx.y * gridDim.x + blockIdx.x;
  bid = (bid & 7) * (nwg >> 3) + (bid >> 3);
  const int bx = bid % gridDim.x, by = bid / gridDim.x;
  const int rowBase = by * 128, colBase = bx * 128;

  if (GATHER) {
    if (tid < 128) sidx[tid] = gidx[rowBase + tid];
    __syncthreads();
  }

  const int srow  = lane >> 2;
  const int sunit = lane & 3;

  auto stageA = [&](int kt, int bb) {
#pragma unroll
    for (int c = 0; c < 2; ++c) {
      const int rowq = (c * 4 + w) * 16 + srow;
      const long arow = GATHER ? (long)sidx[rowq] : (long)(rowBase + rowq);
      const unsigned short* g = A + (size_t)arow * Kpad + kt * 32 + sunit * 8;
      __builtin_amdgcn_global_load_lds(
          (const __attribute__((address_space(1))) unsigned int*)g,
          (__attribute__((address_space(3))) unsigned int*)
              &As[bb][(((c * 4 + w) * 64) + lane) * 8],
          16, 0, 0);
    }
  };
  auto stageB = [&](int kt, int bb) {
#pragma unroll
    for (int c = 0; c < 2; ++c) {
      const int rowq = (c * 4 + w) * 16 + srow;
      const unsigned short* g =
          Bt + (size_t)(colBase + rowq) * Kpad + kt * 32 + sunit * 8;
      __builtin_amdgcn_global_load_lds(
          (const __attribute__((address_space(1))) unsigned int*)g,
          (__attribute__((address_space(3))) unsigned int*)
              &Bs[bb][(((c * 4 + w) * 64) + lane) * 8],
          16, 0, 0);
    }
  };

  f32x4 acc[4][4] = {};
  stageA(0, 0); stageB(0, 0);
  const int nk = Kpad >> 5;
  const int lr = lane >> 4, lc = lane & 15;

  for (int kt = 0; kt < nk; ++kt) {
    const int bb = kt & 1;
    __syncthreads();
    if (kt + 1 < nk) { stageA(kt + 1, bb ^ 1); stageB(kt + 1, bb ^ 1); }
    bf16x8 a[4], b[4];
#pragma unroll
    for (int f = 0; f < 4; ++f) {
      const int ra = wr * 64 + f * 16 + lc;
      a[f] = *reinterpret_cast<const bf16x8*>(&As[bb][ra * 32 + lr * 8]);
      const int rb = wc * 64 + f * 16 + lc;
      b[f] = *reinterpret_cast<const bf16x8*>(&Bs[bb][rb * 32 + lr * 8]);
    }
#pragma unroll
    for (int i = 0; i < 4; ++i)
#pragma unroll
      for (int j = 0; j < 4; ++j)
        acc[i][j] =
            __builtin_amdgcn_mfma_f32_16x16x32_bf16(a[i], b[j], acc[i][j], 0, 0, 0);
  }

  float bce = 0.f;
#pragma unroll
  for (int j = 0; j < 4; ++j) {
    const int gcol = colBase + wc * 64 + j * 16 + lc;
    const float bj = (gcol < N) ? bias[gcol] : 0.f;
#pragma unroll
    for (int i = 0; i < 4; ++i) {
      const int growb = rowBase + wr * 64 + i * 16 + lr * 4;
#pragma unroll
      for (int r = 0; r < 4; ++r) {
        float v = acc[i][j][r] + bj;
        if (ACT == 1) v = fmaxf(v, 0.f);
        float e2 = 0.f, ov = v;
        if (ACT == 2) {
          e2 = __builtin_amdgcn_exp2f(v * -1.442695041f);   // exp(-v)
          ov = __builtin_amdgcn_rcpf(1.f + e2);             // sigmoid
        }
        const int grow = growb + r;
        if (OUTF32) {
          if (gcol < N) {
            ((float*)C)[(size_t)grow * N + gcol] = ov;
            if (BCE) {
              const float L =
                  0.69314718056f * __builtin_amdgcn_logf(1.f + e2);
              const float xv = xg[(size_t)grow * N + gcol];
              bce += (xv - 1.f) * v - L;
            }
          }
        } else {
          if (gcol < NpadOut) {
            const unsigned short hv = (gcol < N) ? f2bf(ov) : (unsigned short)0;
            ((unsigned short*)C)[(size_t)grow * NpadOut + gcol] = hv;
            if (FP8OUT)
              C8[(size_t)grow * NpadOut + gcol] =
                  (unsigned char)((gcol < N) ? f2e4m3(ov * ZSCALE) : 0u);
          }
        }
      }
    }
  }

  if (BCE) {
    rsum[tid] = bce;
    __syncthreads();
#pragma unroll
    for (int s = 128; s > 0; s >>= 1) {
      if (tid < s) rsum[tid] += rsum[tid + s];
      __syncthreads();
    }
    if (tid == 0) atomicAdd(loss_accum, rsum[0]);
  }
}

// ---------------------------------------------------------------------------
// MX-fp8 MFMA VQ argmin -- r13 configuration RESTORED VERBATIM (the proven
// 77.6us / occupancy 19% / VGPR 128 build).  Per-wave unified registers sit
// exactly at the 256 cliff (128 arch + 128 AGPR a[]); r14 (+16 acc) and r15
// (+4 key regs) both crossed it and lost block co-residency -> 92-104us.
// DO NOT grow registers in this kernel.
// 256 thr, 4 waves x 64 rows, mf=4, nf-outer acc4, 32-code tiles,
// 2x16KB LDS -> 2 blocks/CU -> 2 waves/SIMD overlap (m114).
// Grid = 64 rowgroups x 8 chunks = 512 blocks = 2/CU, chunk = bid&7.
// global_load_lds staging with 16B XOR swizzle (LDS[r][u] = G[r][u^(r&7)]).
// score = esqh - acc (esqh = 0.5*SQSCALE*||e||^2); ||z||^2 argmin-invariant.
// ---------------------------------------------------------------------------
__global__ __launch_bounds__(256, 1)
void vq_mfma_kernel(const unsigned char* __restrict__ zef,
                    const unsigned char* __restrict__ embf,
                    const float* __restrict__ esqh,
                    float* __restrict__ cand_val, int* __restrict__ cand_idx) {
  __shared__ __align__(16) unsigned char etile[2][32 * 512];

  const int tid  = threadIdx.x;
  const int w    = tid >> 6, lane = tid & 63;
  const int cq   = lane >> 4, cr = lane & 15;

  const int chunk    = blockIdx.x & 7;
  const int rowblock = blockIdx.x >> 3;    // 0..63
  const int rowBase  = rowblock * 256;
  const int codeBase = chunk * 1024;

  // A fragments: 64 rows/wave.  row = lane&15, per-lane 32 contiguous
  // k-bytes at cq*32 within each K=128 slice (layout verified rounds 5-15).
  i32x8 a[4][4];
  {
    const unsigned char* z0 =
        zef + (size_t)(rowBase + w * 64 + cr) * D_SZ + cq * 32;
#pragma unroll
    for (int mf = 0; mf < 4; ++mf)
#pragma unroll
      for (int ks = 0; ks < 4; ++ks)
        a[mf][ks] =
            *reinterpret_cast<const i32x8*>(z0 + mf * 16 * D_SZ + ks * 128);
  }

  float minv[4][4];
  int   mini[4][4];
#pragma unroll
  for (int mf = 0; mf < 4; ++mf)
#pragma unroll
    for (int r4 = 0; r4 < 4; ++r4) { minv[mf][r4] = FLT_MAX; mini[mf][r4] = 0; }

  // Staging: 32 rows x 512 B = 16 KB per buffer; 256 thr x 16 B x 4 passes.
  const int srow  = tid >> 5;              // 0..7; row&7 == srow (p*8 step)
  const int sunit = tid & 31;              // 16B unit within a 512B row
  const int soff  = (sunit ^ srow) << 4;
  auto stage = [&](int tt, int bb) {
#pragma unroll
    for (int p = 0; p < 4; ++p) {
      const int row = p * 8 + srow;
      const unsigned char* g =
          embf + (size_t)(codeBase + tt * 32 + row) * D_SZ + soff;
      __builtin_amdgcn_global_load_lds(
          (const __attribute__((address_space(1))) unsigned int*)g,
          (__attribute__((address_space(3))) unsigned int*)
              &etile[bb][(p * 8 + w * 2) * 512 + (lane << 4)],
          16, 0, 0);
    }
  };

  stage(0, 0);
  __syncthreads();

  const int swz = cr & 7;
  const char* lds0 = (const char*)etile[0];
  const char* lds1 = (const char*)etile[1];
  const float* esq_c = esqh + codeBase;

  for (int t = 0; t < 32; ++t) {
    const int bb = t & 1;
    if (t + 1 < 32) stage(t + 1, bb ^ 1);
    const char* buf = bb ? lds1 : lds0;
    const int tb = t * 32;

#pragma unroll
    for (int nf = 0; nf < 2; ++nf) {
      const int rb = (nf * 16 + cr) * 512;
      f32x4 acc4[4] = {};
#pragma unroll
      for (int ks = 0; ks < 4; ++ks) {
        const int ub = (ks << 3) + (cq << 1);
        const i32x4 lo =
            *reinterpret_cast<const i32x4*>(buf + rb + ((ub ^ swz) << 4));
        const i32x4 hi =
            *reinterpret_cast<const i32x4*>(buf + rb + (((ub + 1) ^ swz) << 4));
        const i32x8 bv = __builtin_shufflevector(lo, hi, 0, 1, 2, 3, 4, 5, 6, 7);
#pragma unroll
        for (int mf = 0; mf < 4; ++mf)
          acc4[mf] = __builtin_amdgcn_mfma_scale_f32_16x16x128_f8f6f4(
              a[mf][ks], bv, acc4[mf], 0, 0, 0, 0x7F, 0, 0x7F);
      }
      const int cl = tb + nf * 16 + cr;
      const float h = esq_c[cl];
      const int c = codeBase + cl;
#pragma unroll
      for (int mf = 0; mf < 4; ++mf)
#pragma unroll
        for (int r4 = 0; r4 < 4; ++r4) {
          const float s = h - acc4[mf][r4];
          if (s < minv[mf][r4]) { minv[mf][r4] = s; mini[mf][r4] = c; }
        }
    }
    __syncthreads();
  }

  // cross-lane argmin over the 16 column-lanes, tie -> min idx
#pragma unroll
  for (int mf = 0; mf < 4; ++mf)
#pragma unroll
    for (int r4 = 0; r4 < 4; ++r4) {
      float v = minv[mf][r4];
      int   i = mini[mf][r4];
#pragma unroll
      for (int m = 1; m < 16; m <<= 1) {
        float ov = __shfl_xor(v, m, 64);
        int   oi = __shfl_xor(i, m, 64);
        if (ov < v || (ov == v && oi < i)) { v = ov; i = oi; }
      }
      if (cr == 0) {
        const int row = rowBase + w * 64 + mf * 16 + cq * 4 + r4;
        cand_val[(size_t)chunk * B_SZ + row] = v;
        cand_idx[(size_t)chunk * B_SZ + row] = i;
      }
    }
}

// ---------------------------------------------------------------------------
__global__ __launch_bounds__(256)
void vq_finalize_kernel(const float* __restrict__ cv, const int* __restrict__ ci,
                        int* __restrict__ idx) {
  const int r = blockIdx.x * 256 + threadIdx.x;
  float bv = cv[r];
  int   bi = ci[r];
#pragma unroll
  for (int c = 1; c < 8; ++c) {
    const float v = cv[(size_t)c * B_SZ + r];
    const int  i2 = ci[(size_t)c * B_SZ + r];
    if (v < bv || (v == bv && i2 < bi)) { bv = v; bi = i2; }
  }
  idx[r] = bi;
}

// ---------------------------------------------------------------------------
// sum((z_e - emb[idx])^2) -> accum[1], z_e read from bf16 zeb, emb exact fp32
// ---------------------------------------------------------------------------
__global__ __launch_bounds__(256)
void vqloss_kernel(const unsigned short* __restrict__ zeb,
                   const float* __restrict__ emb,
                   const int* __restrict__ idx, float* __restrict__ accum) {
  __shared__ float rsum[256];
  const int tid = threadIdx.x;
  const size_t stride = (size_t)gridDim.x * 256;
  const size_t total = (size_t)B_SZ * (D_SZ / 8);
  float s = 0.f;
  for (size_t e = (size_t)blockIdx.x * 256 + tid; e < total; e += stride) {
    const size_t b = e >> 6;
    const int   d8 = (int)(e & 63);
    bf16x8 z = *reinterpret_cast<const bf16x8*>(zeb + b * D_SZ + d8 * 8);
    const float* q = emb + (size_t)idx[b] * D_SZ + d8 * 8;
    const float4 q0 = *reinterpret_cast<const float4*>(q);
    const float4 q1 = *reinterpret_cast<const float4*>(q + 4);
    const float qa[8] = {q0.x, q0.y, q0.z, q0.w, q1.x, q1.y, q1.z, q1.w};
#pragma unroll
    for (int j = 0; j < 8; ++j) {
      const float d = bf2f((unsigned short)z[j]) - qa[j];
      s += d * d;
    }
  }
  rsum[tid] = s;
  __syncthreads();
#pragma unroll
  for (int st = 128; st > 0; st >>= 1) {
    if (tid < st) rsum[tid] += rsum[tid + st];
    __syncthreads();
  }
  if (tid == 0) atomicAdd(accum + 1, rsum[0]);
}

// ---------------------------------------------------------------------------
__global__ void finalize_kernel(const float* __restrict__ accum,
                                float* __restrict__ out) {
  const float rl = -accum[0] / ((float)B_SZ * (float)DIN);
  const float el = accum[1] / (float)B_SZ;
  out[(size_t)B_SZ * DIN + 0] = rl;
  out[(size_t)B_SZ * DIN + 1] = el;
  out[(size_t)B_SZ * DIN + 2] = el;
}

// ---------------------------------------------------------------------------
extern "C" void kernel_launch(void* const* d_in, const int* in_sizes, int n_in,
                              void* d_out, int out_size, void* d_ws,
                              size_t ws_size, hipStream_t stream) {
  const float* x   = (const float*)d_in[0];
  const float* W1  = (const float*)d_in[1];
  const float* b1  = (const float*)d_in[2];
  const float* W2  = (const float*)d_in[3];
  const float* b2  = (const float*)d_in[4];
  const float* W3  = (const float*)d_in[5];
  const float* b3  = (const float*)d_in[6];
  const float* W4  = (const float*)d_in[7];
  const float* b4  = (const float*)d_in[8];
  const float* emb = (const float*)d_in[9];
  float* out = (float*)d_out;

  // ---- workspace layout ----
  char* wsb = (char*)d_ws;
  auto alloc = [&](size_t bytes) {
    char* p = wsb;
    wsb += (bytes + 255) & ~(size_t)255;
    return p;
  };
  const size_t xb_bytes  = (size_t)B_SZ * DIN_P * 2;   // 26.2 MB
  const size_t zeb_bytes = (size_t)B_SZ * D_SZ * 2;    // 16.8 MB
  char* regionA = alloc(xb_bytes);  // xb; later zeb+embb (xb dead after gemm1)
  unsigned short* xb   = (unsigned short*)regionA;
  unsigned short* zeb  = (unsigned short*)regionA;
  unsigned short* embb = (unsigned short*)(regionA + zeb_bytes);
  char* regionB = alloc((size_t)B_SZ * H_P * 2);       // h1b, later h3b
  unsigned short* h1b = (unsigned short*)regionB;
  unsigned short* h3b = (unsigned short*)regionB;
  unsigned short* W1t = (unsigned short*)alloc((size_t)512 * DIN_P * 2);
  unsigned short* W2t = (unsigned short*)alloc((size_t)512 * H_P * 2);
  unsigned short* W3t = (unsigned short*)alloc((size_t)512 * D_SZ * 2);
  unsigned short* W4t = (unsigned short*)alloc((size_t)896 * H_P * 2);
  unsigned char* zef  = (unsigned char*)alloc((size_t)B_SZ * D_SZ);  // 8.4 MB
  unsigned char* embf = (unsigned char*)alloc((size_t)K_SZ * D_SZ);  // 4.2 MB
  float* esqh  = (float*)alloc((size_t)K_SZ * 4);
  float* accum = (float*)alloc(64);
  int*   idx   = (int*)alloc((size_t)B_SZ * 4);
  float* cand_val = (float*)alloc((size_t)8 * B_SZ * 4);
  int*   cand_idx = (int*)alloc((size_t)8 * B_SZ * 4);

  // 1) bf16 operand prep (weights batched into one launch)
  castpad_x_kernel<<<2048, 256, 0, stream>>>(x, xb);
  WtransArgs wa;
  wa.W[0] = W1;  wa.Wt[0] = W1t; wa.K[0] = DIN;  wa.N[0] = H_SZ;
  wa.Kpad[0] = DIN_P; wa.Npad[0] = 512; wa.gx[0] = 25;   // 25x16 = 400
  wa.W[1] = W2;  wa.Wt[1] = W2t; wa.K[1] = H_SZ; wa.N[1] = D_SZ;
  wa.Kpad[1] = H_P;   wa.Npad[1] = 512; wa.gx[1] = 13;   // 13x16 = 208
  wa.W[2] = W3;  wa.Wt[2] = W3t; wa.K[2] = D_SZ; wa.N[2] = H_SZ;
  wa.Kpad[2] = D_SZ;  wa.Npad[2] = 512; wa.gx[2] = 16;   // 16x16 = 256
  wa.W[3] = W4;  wa.Wt[3] = W4t; wa.K[3] = H_SZ; wa.N[3] = DIN;
  wa.Kpad[3] = H_P;   wa.Npad[3] = 896; wa.gx[3] = 13;   // 13x28 = 364
  wa.off[0] = 0; wa.off[1] = 400; wa.off[2] = 608; wa.off[3] = 864;
  wa.off[4] = 1228;
  wtrans4_kernel<<<1228, 256, 0, stream>>>(wa);
  // 2) h1 = relu(x @ W1 + b1)
  mgemm_kernel<1, false, false, false, false>
      <<<dim3(4, B_SZ / 128), 256, 0, stream>>>(
      xb, W1t, b1, h1b, H_SZ, DIN_P, H_P, nullptr, nullptr, nullptr, nullptr);
  // 3) emb -> bf16 + fp8 + esqh + zero accum (regionA tail free now)
  embprep_kernel<<<K_SZ / 4, 256, 0, stream>>>(emb, embb, embf, esqh, accum);
  // 4) z_e = h1 @ W2 + b2  (bf16 zeb + fp8 zef)
  mgemm_kernel<0, false, false, false, true>
      <<<dim3(4, B_SZ / 128), 256, 0, stream>>>(
      h1b, W2t, b2, zeb, D_SZ, H_P, D_SZ, nullptr, nullptr, nullptr, zef);
  // 5) VQ argmin (MX fp8 MFMA)
  vq_mfma_kernel<<<512, 256, 0, stream>>>(zef, embf, esqh, cand_val, cand_idx);
  vq_finalize_kernel<<<B_SZ / 256, 256, 0, stream>>>(cand_val, cand_idx, idx);
  // 6) embed/commit loss
  vqloss_kernel<<<1024, 256, 0, stream>>>(zeb, emb, idx, accum);
  // 7) h3 = relu(emb[idx] @ W3 + b3)
  mgemm_kernel<1, true, false, false, false>
      <<<dim3(4, B_SZ / 128), 256, 0, stream>>>(
      embb, W3t, b3, h3b, H_SZ, D_SZ, H_P, idx, nullptr, nullptr, nullptr);
  // 8) x_reconst = sigmoid(h3 @ W4 + b4), fused fast BCE
  mgemm_kernel<2, false, true, true, false>
      <<<dim3(7, B_SZ / 128), 256, 0, stream>>>(
      h3b, W4t, b4, out, DIN, H_P, DIN, nullptr, x, accum, nullptr);
  // 9) scalars
  finalize_kernel<<<1, 1, 0, stream>>>(accum, out);
}

// Round 17
// 232.825 us; speedup vs baseline: 1.1672x; 1.0158x over previous
//
#include <hip/hip_runtime.h>
#include <cfloat>
#include <cstddef>

#define B_SZ 16384
#define DIN  784
#define H_SZ 400
#define D_SZ 512
#define K_SZ 8192

#define DIN_P 800   // 784 padded to 25*32
#define H_P   416   // 400 padded to 13*32

#define ZSCALE 64.f
#define ESCALE 256.f
#define SQSCALE (ZSCALE * ESCALE)

typedef short bf16x8 __attribute__((ext_vector_type(8)));
typedef float f32x4  __attribute__((ext_vector_type(4)));
typedef int   i32x4  __attribute__((ext_vector_type(4)));
typedef int   i32x8  __attribute__((ext_vector_type(8)));

__device__ __forceinline__ unsigned short f2bf(float f) {
  unsigned u = __float_as_uint(f);
  unsigned r = (u + 0x7FFFu + ((u >> 16) & 1u)) >> 16;
  return (unsigned short)r;
}
__device__ __forceinline__ float bf2f(unsigned short h) {
  return __uint_as_float(((unsigned)h) << 16);
}
// fp32 -> OCP e4m3fn (RNE in normal range, RN in subnormal, clamp to 448)
__device__ __forceinline__ unsigned f2e4m3(float f) {
  unsigned u = __float_as_uint(f);
  const unsigned sign = (u >> 24) & 0x80u;
  const float af = __uint_as_float(u & 0x7FFFFFFFu);
  if (af >= 448.f) return sign | 0x7Eu;
  if (af < 0.015625f) {                  // subnormal, unit 2^-9
    const int m = (int)(af * 512.f + 0.5f);
    return sign | (unsigned)m;
  }
  u = (u & 0x7FFFFFFFu) + 0x7FFFFu + ((u >> 20) & 1u);
  const unsigned e8 = (u >> 23) - 120u;  // -127+7
  if (e8 >= 16u) return sign | 0x7Eu;
  return sign | (e8 << 3) | ((u >> 20) & 7u);
}

// ---------------------------------------------------------------------------
// Fused emb prep: one pass over emb producing bf16 copy (decode gather),
// fp8*ESCALE copy (VQ scan), esqh = 0.5*SQSCALE*||e||^2, + zero accumulators.
// ---------------------------------------------------------------------------
__global__ __launch_bounds__(256)
void embprep_kernel(const float* __restrict__ emb,
                    unsigned short* __restrict__ embb,
                    unsigned char* __restrict__ embf,
                    float* __restrict__ esqh, float* __restrict__ accum) {
  if (blockIdx.x == 0 && threadIdx.x == 0) { accum[0] = 0.f; accum[1] = 0.f; }
  const int row  = blockIdx.x * 4 + (threadIdx.x >> 6);
  const int lane = threadIdx.x & 63;
  const float* p = emb + (size_t)row * D_SZ + lane * 8;
  const float4 v0 = *reinterpret_cast<const float4*>(p);
  const float4 v1 = *reinterpret_cast<const float4*>(p + 4);

  ushort4 h0, h1;
  h0.x = f2bf(v0.x); h0.y = f2bf(v0.y); h0.z = f2bf(v0.z); h0.w = f2bf(v0.w);
  h1.x = f2bf(v1.x); h1.y = f2bf(v1.y); h1.z = f2bf(v1.z); h1.w = f2bf(v1.w);
  reinterpret_cast<ushort4*>(embb + (size_t)row * D_SZ + lane * 8)[0] = h0;
  reinterpret_cast<ushort4*>(embb + (size_t)row * D_SZ + lane * 8 + 4)[0] = h1;

  uint2 q;
  q.x = f2e4m3(v0.x * ESCALE) | (f2e4m3(v0.y * ESCALE) << 8) |
        (f2e4m3(v0.z * ESCALE) << 16) | (f2e4m3(v0.w * ESCALE) << 24);
  q.y = f2e4m3(v1.x * ESCALE) | (f2e4m3(v1.y * ESCALE) << 8) |
        (f2e4m3(v1.z * ESCALE) << 16) | (f2e4m3(v1.w * ESCALE) << 24);
  *reinterpret_cast<uint2*>(embf + (size_t)row * D_SZ + lane * 8) = q;

  float s = v0.x * v0.x + v0.y * v0.y + v0.z * v0.z + v0.w * v0.w +
            v1.x * v1.x + v1.y * v1.y + v1.z * v1.z + v1.w * v1.w;
#pragma unroll
  for (int off = 32; off > 0; off >>= 1) s += __shfl_down(s, off);
  if (lane == 0) esqh[row] = 0.5f * SQSCALE * s;
}

// ---------------------------------------------------------------------------
// Batched weight transpose: all 4 W [K][N] fp32 -> Wt [Npad][Kpad] bf16 in
// ONE launch.  Flat grid of 32x32 tiles; descriptor-table walk per block.
// ---------------------------------------------------------------------------
struct WtransArgs {
  const float* W[4];
  unsigned short* Wt[4];
  int K[4], N[4], Kpad[4], Npad[4], gx[4], off[5];
};

__global__ __launch_bounds__(256)
void wtrans4_kernel(WtransArgs args) {
  __shared__ float t[32][33];
  const int bid = blockIdx.x;
  int i = 0;
#pragma unroll
  for (int j = 1; j < 4; ++j) i += (bid >= args.off[j]);
  const int local = bid - args.off[i];
  const int k0 = (local % args.gx[i]) * 32;
  const int n0 = (local / args.gx[i]) * 32;
  const float* W = args.W[i];
  unsigned short* Wt = args.Wt[i];
  const int K = args.K[i], N = args.N[i];
  const int Kpad = args.Kpad[i], Npad = args.Npad[i];

  const int tx = threadIdx.x & 31, ty = threadIdx.x >> 5;
#pragma unroll
  for (int s = 0; s < 4; ++s) {
    const int k = k0 + ty + s * 8, n = n0 + tx;
    t[ty + s * 8][tx] = (k < K && n < N) ? W[(size_t)k * N + n] : 0.f;
  }
  __syncthreads();
#pragma unroll
  for (int s = 0; s < 4; ++s) {
    const int n = n0 + ty + s * 8, k = k0 + tx;
    if (n < Npad && k < Kpad)
      Wt[(size_t)n * Kpad + k] = f2bf(t[tx][ty + s * 8]);
  }
}

// ---------------------------------------------------------------------------
// MFMA GEMM: C = act(A @ Bt^T + bias).  BM=BN=128, BK=32, 4 waves (2x2),
// acc 4x4 of 16x16x32 bf16 fragments, double-buffered staging.
// CVTA: A is fp32 [M][784] (raw x); staging converts to bf16 in-register and
// ds_writes the IDENTICAL LDS layout (k>=784 lanes fully zero-padded; 784%8
// ==0 so lanes are never split).  Kills the separate castpad_x pass.
// ACT: 0=none 1=relu 2=sigmoid (fast).  BCE fused (x-1)*v - ln(1+e^-v).
// XCD-chunked block swizzle: bid=(d%8)*(nwg/8)+d/8.
// ---------------------------------------------------------------------------
template <int ACT, bool GATHER, bool BCE, bool OUTF32, bool FP8OUT, bool CVTA>
__global__ __launch_bounds__(256, 3)
void mgemm_kernel(const unsigned short* __restrict__ A,
                  const float* __restrict__ Af,
                  const unsigned short* __restrict__ Bt,
                  const float* __restrict__ bias, void* __restrict__ C,
                  int N, int Kpad, int NpadOut,
                  const int* __restrict__ gidx,
                  const float* __restrict__ xg, float* __restrict__ loss_accum,
                  unsigned char* __restrict__ C8) {
  __shared__ __align__(16) unsigned short As[2][128 * 32];
  __shared__ __align__(16) unsigned short Bs[2][128 * 32];
  __shared__ int   sidx[128];
  __shared__ float rsum[256];

  const int tid  = threadIdx.x;
  const int w    = tid >> 6, lane = tid & 63;
  const int wr   = w >> 1, wc = w & 1;

  const int nwg = gridDim.x * gridDim.y;
  int bid = blockIdx.y * gridDim.x + blockIdx.x;
  bid = (bid & 7) * (nwg >> 3) + (bid >> 3);
  const int bx = bid % gridDim.x, by = bid / gridDim.x;
  const int rowBase = by * 128, colBase = bx * 128;

  if (GATHER) {
    if (tid < 128) sidx[tid] = gidx[rowBase + tid];
    __syncthreads();
  }

  const int srow  = lane >> 2;
  const int sunit = lane & 3;

  auto stageA = [&](int kt, int bb) {
#pragma unroll
    for (int c = 0; c < 2; ++c) {
      const int rowq = (c * 4 + w) * 16 + srow;
      if (CVTA) {
        const int grow = rowBase + rowq;
        const int k0 = kt * 32 + sunit * 8;
        bf16x8 v8 = {};
        if (k0 < DIN) {
          const float* xp = Af + (size_t)grow * DIN + k0;
          const float4 f0 = *reinterpret_cast<const float4*>(xp);
          const float4 f1 = *reinterpret_cast<const float4*>(xp + 4);
          v8[0] = (short)f2bf(f0.x); v8[1] = (short)f2bf(f0.y);
          v8[2] = (short)f2bf(f0.z); v8[3] = (short)f2bf(f0.w);
          v8[4] = (short)f2bf(f1.x); v8[5] = (short)f2bf(f1.y);
          v8[6] = (short)f2bf(f1.z); v8[7] = (short)f2bf(f1.w);
        }
        *reinterpret_cast<bf16x8*>(&As[bb][(((c * 4 + w) * 64) + lane) * 8]) = v8;
      } else {
        const long arow = GATHER ? (long)sidx[rowq] : (long)(rowBase + rowq);
        const unsigned short* g = A + (size_t)arow * Kpad + kt * 32 + sunit * 8;
        __builtin_amdgcn_global_load_lds(
            (const __attribute__((address_space(1))) unsigned int*)g,
            (__attribute__((address_space(3))) unsigned int*)
                &As[bb][(((c * 4 + w) * 64) + lane) * 8],
            16, 0, 0);
      }
    }
  };
  auto stageB = [&](int kt, int bb) {
#pragma unroll
    for (int c = 0; c < 2; ++c) {
      const int rowq = (c * 4 + w) * 16 + srow;
      const unsigned short* g =
          Bt + (size_t)(colBase + rowq) * Kpad + kt * 32 + sunit * 8;
      __builtin_amdgcn_global_load_lds(
          (const __attribute__((address_space(1))) unsigned int*)g,
          (__attribute__((address_space(3))) unsigned int*)
              &Bs[bb][(((c * 4 + w) * 64) + lane) * 8],
          16, 0, 0);
    }
  };

  f32x4 acc[4][4] = {};
  stageA(0, 0); stageB(0, 0);
  const int nk = Kpad >> 5;
  const int lr = lane >> 4, lc = lane & 15;

  for (int kt = 0; kt < nk; ++kt) {
    const int bb = kt & 1;
    __syncthreads();
    if (kt + 1 < nk) { stageA(kt + 1, bb ^ 1); stageB(kt + 1, bb ^ 1); }
    bf16x8 a[4], b[4];
#pragma unroll
    for (int f = 0; f < 4; ++f) {
      const int ra = wr * 64 + f * 16 + lc;
      a[f] = *reinterpret_cast<const bf16x8*>(&As[bb][ra * 32 + lr * 8]);
      const int rb = wc * 64 + f * 16 + lc;
      b[f] = *reinterpret_cast<const bf16x8*>(&Bs[bb][rb * 32 + lr * 8]);
    }
#pragma unroll
    for (int i = 0; i < 4; ++i)
#pragma unroll
      for (int j = 0; j < 4; ++j)
        acc[i][j] =
            __builtin_amdgcn_mfma_f32_16x16x32_bf16(a[i], b[j], acc[i][j], 0, 0, 0);
  }

  float bce = 0.f;
#pragma unroll
  for (int j = 0; j < 4; ++j) {
    const int gcol = colBase + wc * 64 + j * 16 + lc;
    const float bj = (gcol < N) ? bias[gcol] : 0.f;
#pragma unroll
    for (int i = 0; i < 4; ++i) {
      const int growb = rowBase + wr * 64 + i * 16 + lr * 4;
#pragma unroll
      for (int r = 0; r < 4; ++r) {
        float v = acc[i][j][r] + bj;
        if (ACT == 1) v = fmaxf(v, 0.f);
        float e2 = 0.f, ov = v;
        if (ACT == 2) {
          e2 = __builtin_amdgcn_exp2f(v * -1.442695041f);   // exp(-v)
          ov = __builtin_amdgcn_rcpf(1.f + e2);             // sigmoid
        }
        const int grow = growb + r;
        if (OUTF32) {
          if (gcol < N) {
            ((float*)C)[(size_t)grow * N + gcol] = ov;
            if (BCE) {
              const float L =
                  0.69314718056f * __builtin_amdgcn_logf(1.f + e2);
              const float xv = xg[(size_t)grow * N + gcol];
              bce += (xv - 1.f) * v - L;
            }
          }
        } else {
          if (gcol < NpadOut) {
            const unsigned short hv = (gcol < N) ? f2bf(ov) : (unsigned short)0;
            ((unsigned short*)C)[(size_t)grow * NpadOut + gcol] = hv;
            if (FP8OUT)
              C8[(size_t)grow * NpadOut + gcol] =
                  (unsigned char)((gcol < N) ? f2e4m3(ov * ZSCALE) : 0u);
          }
        }
      }
    }
  }

  if (BCE) {
    rsum[tid] = bce;
    __syncthreads();
#pragma unroll
    for (int s = 128; s > 0; s >>= 1) {
      if (tid < s) rsum[tid] += rsum[tid + s];
      __syncthreads();
    }
    if (tid == 0) atomicAdd(loss_accum, rsum[0]);
  }
}

// ---------------------------------------------------------------------------
// MX-fp8 MFMA VQ argmin -- r13 configuration, UNCHANGED (77.6us, VGPR 128,
// occupancy 19%).  Per-wave unified registers sit exactly at the 256 cliff
// (128 arch + 128 AGPR a[]); any register growth loses block co-residency
// (r14: +16 -> 104us, r15: +4 -> 92us).  DO NOT touch.
// ---------------------------------------------------------------------------
__global__ __launch_bounds__(256, 1)
void vq_mfma_kernel(const unsigned char* __restrict__ zef,
                    const unsigned char* __restrict__ embf,
                    const float* __restrict__ esqh,
                    float* __restrict__ cand_val, int* __restrict__ cand_idx) {
  __shared__ __align__(16) unsigned char etile[2][32 * 512];

  const int tid  = threadIdx.x;
  const int w    = tid >> 6, lane = tid & 63;
  const int cq   = lane >> 4, cr = lane & 15;

  const int chunk    = blockIdx.x & 7;
  const int rowblock = blockIdx.x >> 3;    // 0..63
  const int rowBase  = rowblock * 256;
  const int codeBase = chunk * 1024;

  i32x8 a[4][4];
  {
    const unsigned char* z0 =
        zef + (size_t)(rowBase + w * 64 + cr) * D_SZ + cq * 32;
#pragma unroll
    for (int mf = 0; mf < 4; ++mf)
#pragma unroll
      for (int ks = 0; ks < 4; ++ks)
        a[mf][ks] =
            *reinterpret_cast<const i32x8*>(z0 + mf * 16 * D_SZ + ks * 128);
  }

  float minv[4][4];
  int   mini[4][4];
#pragma unroll
  for (int mf = 0; mf < 4; ++mf)
#pragma unroll
    for (int r4 = 0; r4 < 4; ++r4) { minv[mf][r4] = FLT_MAX; mini[mf][r4] = 0; }

  const int srow  = tid >> 5;
  const int sunit = tid & 31;
  const int soff  = (sunit ^ srow) << 4;
  auto stage = [&](int tt, int bb) {
#pragma unroll
    for (int p = 0; p < 4; ++p) {
      const int row = p * 8 + srow;
      const unsigned char* g =
          embf + (size_t)(codeBase + tt * 32 + row) * D_SZ + soff;
      __builtin_amdgcn_global_load_lds(
          (const __attribute__((address_space(1))) unsigned int*)g,
          (__attribute__((address_space(3))) unsigned int*)
              &etile[bb][(p * 8 + w * 2) * 512 + (lane << 4)],
          16, 0, 0);
    }
  };

  stage(0, 0);
  __syncthreads();

  const int swz = cr & 7;
  const char* lds0 = (const char*)etile[0];
  const char* lds1 = (const char*)etile[1];
  const float* esq_c = esqh + codeBase;

  for (int t = 0; t < 32; ++t) {
    const int bb = t & 1;
    if (t + 1 < 32) stage(t + 1, bb ^ 1);
    const char* buf = bb ? lds1 : lds0;
    const int tb = t * 32;

#pragma unroll
    for (int nf = 0; nf < 2; ++nf) {
      const int rb = (nf * 16 + cr) * 512;
      f32x4 acc4[4] = {};
#pragma unroll
      for (int ks = 0; ks < 4; ++ks) {
        const int ub = (ks << 3) + (cq << 1);
        const i32x4 lo =
            *reinterpret_cast<const i32x4*>(buf + rb + ((ub ^ swz) << 4));
        const i32x4 hi =
            *reinterpret_cast<const i32x4*>(buf + rb + (((ub + 1) ^ swz) << 4));
        const i32x8 bv = __builtin_shufflevector(lo, hi, 0, 1, 2, 3, 4, 5, 6, 7);
#pragma unroll
        for (int mf = 0; mf < 4; ++mf)
          acc4[mf] = __builtin_amdgcn_mfma_scale_f32_16x16x128_f8f6f4(
              a[mf][ks], bv, acc4[mf], 0, 0, 0, 0x7F, 0, 0x7F);
      }
      const int cl = tb + nf * 16 + cr;
      const float h = esq_c[cl];
      const int c = codeBase + cl;
#pragma unroll
      for (int mf = 0; mf < 4; ++mf)
#pragma unroll
        for (int r4 = 0; r4 < 4; ++r4) {
          const float s = h - acc4[mf][r4];
          if (s < minv[mf][r4]) { minv[mf][r4] = s; mini[mf][r4] = c; }
        }
    }
    __syncthreads();
  }

#pragma unroll
  for (int mf = 0; mf < 4; ++mf)
#pragma unroll
    for (int r4 = 0; r4 < 4; ++r4) {
      float v = minv[mf][r4];
      int   i = mini[mf][r4];
#pragma unroll
      for (int m = 1; m < 16; m <<= 1) {
        float ov = __shfl_xor(v, m, 64);
        int   oi = __shfl_xor(i, m, 64);
        if (ov < v || (ov == v && oi < i)) { v = ov; i = oi; }
      }
      if (cr == 0) {
        const int row = rowBase + w * 64 + mf * 16 + cq * 4 + r4;
        cand_val[(size_t)chunk * B_SZ + row] = v;
        cand_idx[(size_t)chunk * B_SZ + row] = i;
      }
    }
}

// ---------------------------------------------------------------------------
// Fused VQ finalize + loss: block handles 16 rows.  Lanes 0-15 reduce the 8
// chunk candidates for one row each (-> idx[] and LDS), then all 256 threads
// compute sum((zeb - emb[idx])^2) for those rows.  Saves one launch.
// ---------------------------------------------------------------------------
__global__ __launch_bounds__(256)
void vqloss_kernel(const unsigned short* __restrict__ zeb,
                   const float* __restrict__ emb,
                   const float* __restrict__ cv, const int* __restrict__ ci,
                   int* __restrict__ idx, float* __restrict__ accum) {
  __shared__ int   srow_idx[16];
  __shared__ float rsum[256];
  const int tid = threadIdx.x;
  const int r0  = blockIdx.x * 16;

  if (tid < 16) {
    const int r = r0 + tid;
    float bv = cv[r];
    int   bi = ci[r];
#pragma unroll
    for (int c = 1; c < 8; ++c) {
      const float v = cv[(size_t)c * B_SZ + r];
      const int  i2 = ci[(size_t)c * B_SZ + r];
      if (v < bv || (v == bv && i2 < bi)) { bv = v; bi = i2; }
    }
    srow_idx[tid] = bi;
    idx[r] = bi;
  }
  __syncthreads();

  const int lrow = tid >> 4;            // 0..15
  const int lu   = tid & 15;            // unit group
  const unsigned short* z = zeb + (size_t)(r0 + lrow) * D_SZ;
  const float* q = emb + (size_t)srow_idx[lrow] * D_SZ;
  float s = 0.f;
#pragma unroll
  for (int it = 0; it < 4; ++it) {
    const int d8 = lu + it * 16;        // 0..63
    bf16x8 zv = *reinterpret_cast<const bf16x8*>(z + d8 * 8);
    const float4 q0 = *reinterpret_cast<const float4*>(q + d8 * 8);
    const float4 q1 = *reinterpret_cast<const float4*>(q + d8 * 8 + 4);
    const float qa[8] = {q0.x, q0.y, q0.z, q0.w, q1.x, q1.y, q1.z, q1.w};
#pragma unroll
    for (int j = 0; j < 8; ++j) {
      const float d = bf2f((unsigned short)zv[j]) - qa[j];
      s += d * d;
    }
  }
  rsum[tid] = s;
  __syncthreads();
#pragma unroll
  for (int st = 128; st > 0; st >>= 1) {
    if (tid < st) rsum[tid] += rsum[tid + st];
    __syncthreads();
  }
  if (tid == 0) atomicAdd(accum + 1, rsum[0]);
}

// ---------------------------------------------------------------------------
__global__ void finalize_kernel(const float* __restrict__ accum,
                                float* __restrict__ out) {
  const float rl = -accum[0] / ((float)B_SZ * (float)DIN);
  const float el = accum[1] / (float)B_SZ;
  out[(size_t)B_SZ * DIN + 0] = rl;
  out[(size_t)B_SZ * DIN + 1] = el;
  out[(size_t)B_SZ * DIN + 2] = el;
}

// ---------------------------------------------------------------------------
extern "C" void kernel_launch(void* const* d_in, const int* in_sizes, int n_in,
                              void* d_out, int out_size, void* d_ws,
                              size_t ws_size, hipStream_t stream) {
  const float* x   = (const float*)d_in[0];
  const float* W1  = (const float*)d_in[1];
  const float* b1  = (const float*)d_in[2];
  const float* W2  = (const float*)d_in[3];
  const float* b2  = (const float*)d_in[4];
  const float* W3  = (const float*)d_in[5];
  const float* b3  = (const float*)d_in[6];
  const float* W4  = (const float*)d_in[7];
  const float* b4  = (const float*)d_in[8];
  const float* emb = (const float*)d_in[9];
  float* out = (float*)d_out;

  // ---- workspace layout ----
  char* wsb = (char*)d_ws;
  auto alloc = [&](size_t bytes) {
    char* p = wsb;
    wsb += (bytes + 255) & ~(size_t)255;
    return p;
  };
  unsigned short* zeb  = (unsigned short*)alloc((size_t)B_SZ * D_SZ * 2);
  unsigned short* embb = (unsigned short*)alloc((size_t)K_SZ * D_SZ * 2);
  char* regionB = alloc((size_t)B_SZ * H_P * 2);       // h1b, later h3b
  unsigned short* h1b = (unsigned short*)regionB;
  unsigned short* h3b = (unsigned short*)regionB;
  unsigned short* W1t = (unsigned short*)alloc((size_t)512 * DIN_P * 2);
  unsigned short* W2t = (unsigned short*)alloc((size_t)512 * H_P * 2);
  unsigned short* W3t = (unsigned short*)alloc((size_t)512 * D_SZ * 2);
  unsigned short* W4t = (unsigned short*)alloc((size_t)896 * H_P * 2);
  unsigned char* zef  = (unsigned char*)alloc((size_t)B_SZ * D_SZ);  // 8.4 MB
  unsigned char* embf = (unsigned char*)alloc((size_t)K_SZ * D_SZ);  // 4.2 MB
  float* esqh  = (float*)alloc((size_t)K_SZ * 4);
  float* accum = (float*)alloc(64);
  int*   idx   = (int*)alloc((size_t)B_SZ * 4);
  float* cand_val = (float*)alloc((size_t)8 * B_SZ * 4);
  int*   cand_idx = (int*)alloc((size_t)8 * B_SZ * 4);

  // 1) operand prep (weights batched into one launch; x converts in gemm1)
  WtransArgs wa;
  wa.W[0] = W1;  wa.Wt[0] = W1t; wa.K[0] = DIN;  wa.N[0] = H_SZ;
  wa.Kpad[0] = DIN_P; wa.Npad[0] = 512; wa.gx[0] = 25;   // 25x16 = 400
  wa.W[1] = W2;  wa.Wt[1] = W2t; wa.K[1] = H_SZ; wa.N[1] = D_SZ;
  wa.Kpad[1] = H_P;   wa.Npad[1] = 512; wa.gx[1] = 13;   // 13x16 = 208
  wa.W[2] = W3;  wa.Wt[2] = W3t; wa.K[2] = D_SZ; wa.N[2] = H_SZ;
  wa.Kpad[2] = D_SZ;  wa.Npad[2] = 512; wa.gx[2] = 16;   // 16x16 = 256
  wa.W[3] = W4;  wa.Wt[3] = W4t; wa.K[3] = H_SZ; wa.N[3] = DIN;
  wa.Kpad[3] = H_P;   wa.Npad[3] = 896; wa.gx[3] = 13;   // 13x28 = 364
  wa.off[0] = 0; wa.off[1] = 400; wa.off[2] = 608; wa.off[3] = 864;
  wa.off[4] = 1228;
  wtrans4_kernel<<<1228, 256, 0, stream>>>(wa);
  // 2) h1 = relu(x @ W1 + b1)   (A converted fp32->bf16 in staging)
  mgemm_kernel<1, false, false, false, false, true>
      <<<dim3(4, B_SZ / 128), 256, 0, stream>>>(
      nullptr, x, W1t, b1, h1b, H_SZ, DIN_P, H_P, nullptr, nullptr, nullptr,
      nullptr);
  // 3) emb -> bf16 + fp8 + esqh + zero accum
  embprep_kernel<<<K_SZ / 4, 256, 0, stream>>>(emb, embb, embf, esqh, accum);
  // 4) z_e = h1 @ W2 + b2  (bf16 zeb + fp8 zef)
  mgemm_kernel<0, false, false, false, true, false>
      <<<dim3(4, B_SZ / 128), 256, 0, stream>>>(
      h1b, nullptr, W2t, b2, zeb, D_SZ, H_P, D_SZ, nullptr, nullptr, nullptr,
      zef);
  // 5) VQ argmin (MX fp8 MFMA)
  vq_mfma_kernel<<<512, 256, 0, stream>>>(zef, embf, esqh, cand_val, cand_idx);
  // 6) fused finalize + embed/commit loss
  vqloss_kernel<<<B_SZ / 16, 256, 0, stream>>>(zeb, emb, cand_val, cand_idx,
                                               idx, accum);
  // 7) h3 = relu(emb[idx] @ W3 + b3)
  mgemm_kernel<1, true, false, false, false, false>
      <<<dim3(4, B_SZ / 128), 256, 0, stream>>>(
      embb, nullptr, W3t, b3, h3b, H_SZ, D_SZ, H_P, idx, nullptr, nullptr,
      nullptr);
  // 8) x_reconst = sigmoid(h3 @ W4 + b4), fused fast BCE
  mgemm_kernel<2, false, true, true, false, false>
      <<<dim3(7, B_SZ / 128), 256, 0, stream>>>(
      h3b, nullptr, W4t, b4, out, DIN, H_P, DIN, nullptr, x, accum, nullptr);
  // 9) scalars
  finalize_kernel<<<1, 1, 0, stream>>>(accum, out);
}

// Round 18
// 229.133 us; speedup vs baseline: 1.1860x; 1.0161x over previous
//
#include <hip/hip_runtime.h>
#include <cfloat>
#include <cstddef>

#define B_SZ 16384
#define DIN  784
#define H_SZ 400
#define D_SZ 512
#define K_SZ 8192

#define DIN_P 800   // 784 padded to 25*32
#define H_P   416   // 400 padded to 13*32

#define ZSCALE 64.f
#define ESCALE 256.f
#define SQSCALE (ZSCALE * ESCALE)

typedef short bf16x8 __attribute__((ext_vector_type(8)));
typedef float f32x4  __attribute__((ext_vector_type(4)));
typedef int   i32x4  __attribute__((ext_vector_type(4)));
typedef int   i32x8  __attribute__((ext_vector_type(8)));

__device__ __forceinline__ unsigned short f2bf(float f) {
  unsigned u = __float_as_uint(f);
  unsigned r = (u + 0x7FFFu + ((u >> 16) & 1u)) >> 16;
  return (unsigned short)r;
}
__device__ __forceinline__ float bf2f(unsigned short h) {
  return __uint_as_float(((unsigned)h) << 16);
}
// fp32 -> OCP e4m3fn (RNE in normal range, RN in subnormal, clamp to 448)
__device__ __forceinline__ unsigned f2e4m3(float f) {
  unsigned u = __float_as_uint(f);
  const unsigned sign = (u >> 24) & 0x80u;
  const float af = __uint_as_float(u & 0x7FFFFFFFu);
  if (af >= 448.f) return sign | 0x7Eu;
  if (af < 0.015625f) {                  // subnormal, unit 2^-9
    const int m = (int)(af * 512.f + 0.5f);
    return sign | (unsigned)m;
  }
  u = (u & 0x7FFFFFFFu) + 0x7FFFFu + ((u >> 20) & 1u);
  const unsigned e8 = (u >> 23) - 120u;  // -127+7
  if (e8 >= 16u) return sign | 0x7Eu;
  return sign | (e8 << 3) | ((u >> 20) & 7u);
}

// ---------------------------------------------------------------------------
// Combined prep: blocks [0,1228) do the 4 weight transposes (32x32 LDS
// tiles); blocks [1228, 1228+2048) do emb prep (bf16 + fp8 + esqh + zero
// accum).  One launch replaces two.
// ---------------------------------------------------------------------------
struct PrepArgs {
  const float* W[4];
  unsigned short* Wt[4];
  int K[4], N[4], Kpad[4], Npad[4], gx[4], off[5];
  const float* emb;
  unsigned short* embb;
  unsigned char* embf;
  float* esqh;
  float* accum;
};

__global__ __launch_bounds__(256)
void prep_kernel(PrepArgs args) {
  __shared__ float t[32][33];
  const int bid = blockIdx.x;

  if (bid >= args.off[4]) {
    // ---- emb prep path ----
    const int eb = bid - args.off[4];
    if (eb == 0 && threadIdx.x == 0) { args.accum[0] = 0.f; args.accum[1] = 0.f; }
    const int row  = eb * 4 + (threadIdx.x >> 6);
    const int lane = threadIdx.x & 63;
    const float* p = args.emb + (size_t)row * D_SZ + lane * 8;
    const float4 v0 = *reinterpret_cast<const float4*>(p);
    const float4 v1 = *reinterpret_cast<const float4*>(p + 4);

    ushort4 h0, h1;
    h0.x = f2bf(v0.x); h0.y = f2bf(v0.y); h0.z = f2bf(v0.z); h0.w = f2bf(v0.w);
    h1.x = f2bf(v1.x); h1.y = f2bf(v1.y); h1.z = f2bf(v1.z); h1.w = f2bf(v1.w);
    reinterpret_cast<ushort4*>(args.embb + (size_t)row * D_SZ + lane * 8)[0] = h0;
    reinterpret_cast<ushort4*>(args.embb + (size_t)row * D_SZ + lane * 8 + 4)[0] = h1;

    uint2 q;
    q.x = f2e4m3(v0.x * ESCALE) | (f2e4m3(v0.y * ESCALE) << 8) |
          (f2e4m3(v0.z * ESCALE) << 16) | (f2e4m3(v0.w * ESCALE) << 24);
    q.y = f2e4m3(v1.x * ESCALE) | (f2e4m3(v1.y * ESCALE) << 8) |
          (f2e4m3(v1.z * ESCALE) << 16) | (f2e4m3(v1.w * ESCALE) << 24);
    *reinterpret_cast<uint2*>(args.embf + (size_t)row * D_SZ + lane * 8) = q;

    float s = v0.x * v0.x + v0.y * v0.y + v0.z * v0.z + v0.w * v0.w +
              v1.x * v1.x + v1.y * v1.y + v1.z * v1.z + v1.w * v1.w;
#pragma unroll
    for (int off = 32; off > 0; off >>= 1) s += __shfl_down(s, off);
    if (lane == 0) args.esqh[row] = 0.5f * SQSCALE * s;
    return;
  }

  // ---- weight transpose path ----
  int i = 0;
#pragma unroll
  for (int j = 1; j < 4; ++j) i += (bid >= args.off[j]);
  const int local = bid - args.off[i];
  const int k0 = (local % args.gx[i]) * 32;
  const int n0 = (local / args.gx[i]) * 32;
  const float* W = args.W[i];
  unsigned short* Wt = args.Wt[i];
  const int K = args.K[i], N = args.N[i];
  const int Kpad = args.Kpad[i], Npad = args.Npad[i];

  const int tx = threadIdx.x & 31, ty = threadIdx.x >> 5;
#pragma unroll
  for (int s = 0; s < 4; ++s) {
    const int k = k0 + ty + s * 8, n = n0 + tx;
    t[ty + s * 8][tx] = (k < K && n < N) ? W[(size_t)k * N + n] : 0.f;
  }
  __syncthreads();
#pragma unroll
  for (int s = 0; s < 4; ++s) {
    const int n = n0 + ty + s * 8, k = k0 + tx;
    if (n < Npad && k < Kpad)
      Wt[(size_t)n * Kpad + k] = f2bf(t[tx][ty + s * 8]);
  }
}

// ---------------------------------------------------------------------------
// MFMA GEMM: C = act(A @ Bt^T + bias).  BM=BN=128, BK=32, 4 waves (2x2),
// acc 4x4 of 16x16x32 bf16 fragments, double-buffered staging.
// CVTA: A is fp32 [M][784] (raw x); staging converts to bf16 in-register and
// ds_writes the IDENTICAL LDS layout.  ACT: 0=none 1=relu 2=sigmoid (fast).
// BCE fused (x-1)*v - ln(1+e^-v).  XCD-chunked swizzle.
// ---------------------------------------------------------------------------
template <int ACT, bool GATHER, bool BCE, bool OUTF32, bool FP8OUT, bool CVTA>
__global__ __launch_bounds__(256, 3)
void mgemm_kernel(const unsigned short* __restrict__ A,
                  const float* __restrict__ Af,
                  const unsigned short* __restrict__ Bt,
                  const float* __restrict__ bias, void* __restrict__ C,
                  int N, int Kpad, int NpadOut,
                  const int* __restrict__ gidx,
                  const float* __restrict__ xg, float* __restrict__ loss_accum,
                  unsigned char* __restrict__ C8) {
  __shared__ __align__(16) unsigned short As[2][128 * 32];
  __shared__ __align__(16) unsigned short Bs[2][128 * 32];
  __shared__ int   sidx[128];
  __shared__ float rsum[256];

  const int tid  = threadIdx.x;
  const int w    = tid >> 6, lane = tid & 63;
  const int wr   = w >> 1, wc = w & 1;

  const int nwg = gridDim.x * gridDim.y;
  int bid = blockIdx.y * gridDim.x + blockIdx.x;
  bid = (bid & 7) * (nwg >> 3) + (bid >> 3);
  const int bx = bid % gridDim.x, by = bid / gridDim.x;
  const int rowBase = by * 128, colBase = bx * 128;

  if (GATHER) {
    if (tid < 128) sidx[tid] = gidx[rowBase + tid];
    __syncthreads();
  }

  const int srow  = lane >> 2;
  const int sunit = lane & 3;

  auto stageA = [&](int kt, int bb) {
#pragma unroll
    for (int c = 0; c < 2; ++c) {
      const int rowq = (c * 4 + w) * 16 + srow;
      if (CVTA) {
        const int grow = rowBase + rowq;
        const int k0 = kt * 32 + sunit * 8;
        bf16x8 v8 = {};
        if (k0 < DIN) {
          const float* xp = Af + (size_t)grow * DIN + k0;
          const float4 f0 = *reinterpret_cast<const float4*>(xp);
          const float4 f1 = *reinterpret_cast<const float4*>(xp + 4);
          v8[0] = (short)f2bf(f0.x); v8[1] = (short)f2bf(f0.y);
          v8[2] = (short)f2bf(f0.z); v8[3] = (short)f2bf(f0.w);
          v8[4] = (short)f2bf(f1.x); v8[5] = (short)f2bf(f1.y);
          v8[6] = (short)f2bf(f1.z); v8[7] = (short)f2bf(f1.w);
        }
        *reinterpret_cast<bf16x8*>(&As[bb][(((c * 4 + w) * 64) + lane) * 8]) = v8;
      } else {
        const long arow = GATHER ? (long)sidx[rowq] : (long)(rowBase + rowq);
        const unsigned short* g = A + (size_t)arow * Kpad + kt * 32 + sunit * 8;
        __builtin_amdgcn_global_load_lds(
            (const __attribute__((address_space(1))) unsigned int*)g,
            (__attribute__((address_space(3))) unsigned int*)
                &As[bb][(((c * 4 + w) * 64) + lane) * 8],
            16, 0, 0);
      }
    }
  };
  auto stageB = [&](int kt, int bb) {
#pragma unroll
    for (int c = 0; c < 2; ++c) {
      const int rowq = (c * 4 + w) * 16 + srow;
      const unsigned short* g =
          Bt + (size_t)(colBase + rowq) * Kpad + kt * 32 + sunit * 8;
      __builtin_amdgcn_global_load_lds(
          (const __attribute__((address_space(1))) unsigned int*)g,
          (__attribute__((address_space(3))) unsigned int*)
              &Bs[bb][(((c * 4 + w) * 64) + lane) * 8],
          16, 0, 0);
    }
  };

  f32x4 acc[4][4] = {};
  stageA(0, 0); stageB(0, 0);
  const int nk = Kpad >> 5;
  const int lr = lane >> 4, lc = lane & 15;

  for (int kt = 0; kt < nk; ++kt) {
    const int bb = kt & 1;
    __syncthreads();
    if (kt + 1 < nk) { stageA(kt + 1, bb ^ 1); stageB(kt + 1, bb ^ 1); }
    bf16x8 a[4], b[4];
#pragma unroll
    for (int f = 0; f < 4; ++f) {
      const int ra = wr * 64 + f * 16 + lc;
      a[f] = *reinterpret_cast<const bf16x8*>(&As[bb][ra * 32 + lr * 8]);
      const int rb = wc * 64 + f * 16 + lc;
      b[f] = *reinterpret_cast<const bf16x8*>(&Bs[bb][rb * 32 + lr * 8]);
    }
#pragma unroll
    for (int i = 0; i < 4; ++i)
#pragma unroll
      for (int j = 0; j < 4; ++j)
        acc[i][j] =
            __builtin_amdgcn_mfma_f32_16x16x32_bf16(a[i], b[j], acc[i][j], 0, 0, 0);
  }

  float bce = 0.f;
#pragma unroll
  for (int j = 0; j < 4; ++j) {
    const int gcol = colBase + wc * 64 + j * 16 + lc;
    const float bj = (gcol < N) ? bias[gcol] : 0.f;
#pragma unroll
    for (int i = 0; i < 4; ++i) {
      const int growb = rowBase + wr * 64 + i * 16 + lr * 4;
#pragma unroll
      for (int r = 0; r < 4; ++r) {
        float v = acc[i][j][r] + bj;
        if (ACT == 1) v = fmaxf(v, 0.f);
        float e2 = 0.f, ov = v;
        if (ACT == 2) {
          e2 = __builtin_amdgcn_exp2f(v * -1.442695041f);   // exp(-v)
          ov = __builtin_amdgcn_rcpf(1.f + e2);             // sigmoid
        }
        const int grow = growb + r;
        if (OUTF32) {
          if (gcol < N) {
            ((float*)C)[(size_t)grow * N + gcol] = ov;
            if (BCE) {
              const float L =
                  0.69314718056f * __builtin_amdgcn_logf(1.f + e2);
              const float xv = xg[(size_t)grow * N + gcol];
              bce += (xv - 1.f) * v - L;
            }
          }
        } else {
          if (gcol < NpadOut) {
            const unsigned short hv = (gcol < N) ? f2bf(ov) : (unsigned short)0;
            ((unsigned short*)C)[(size_t)grow * NpadOut + gcol] = hv;
            if (FP8OUT)
              C8[(size_t)grow * NpadOut + gcol] =
                  (unsigned char)((gcol < N) ? f2e4m3(ov * ZSCALE) : 0u);
          }
        }
      }
    }
  }

  if (BCE) {
    rsum[tid] = bce;
    __syncthreads();
#pragma unroll
    for (int s = 128; s > 0; s >>= 1) {
      if (tid < s) rsum[tid] += rsum[tid + s];
      __syncthreads();
    }
    if (tid == 0) atomicAdd(loss_accum, rsum[0]);
  }
}

// ---------------------------------------------------------------------------
// MX-fp8 MFMA VQ argmin -- r13 configuration, UNCHANGED (77.6us, VGPR 128,
// occupancy 19%).  Per-wave unified registers sit exactly at the 256 cliff
// (128 arch + 128 AGPR a[]); any register growth loses block co-residency
// (r14: +16 -> 104us, r15: +4 -> 92us).  DO NOT touch.
// ---------------------------------------------------------------------------
__global__ __launch_bounds__(256, 1)
void vq_mfma_kernel(const unsigned char* __restrict__ zef,
                    const unsigned char* __restrict__ embf,
                    const float* __restrict__ esqh,
                    float* __restrict__ cand_val, int* __restrict__ cand_idx) {
  __shared__ __align__(16) unsigned char etile[2][32 * 512];

  const int tid  = threadIdx.x;
  const int w    = tid >> 6, lane = tid & 63;
  const int cq   = lane >> 4, cr = lane & 15;

  const int chunk    = blockIdx.x & 7;
  const int rowblock = blockIdx.x >> 3;    // 0..63
  const int rowBase  = rowblock * 256;
  const int codeBase = chunk * 1024;

  i32x8 a[4][4];
  {
    const unsigned char* z0 =
        zef + (size_t)(rowBase + w * 64 + cr) * D_SZ + cq * 32;
#pragma unroll
    for (int mf = 0; mf < 4; ++mf)
#pragma unroll
      for (int ks = 0; ks < 4; ++ks)
        a[mf][ks] =
            *reinterpret_cast<const i32x8*>(z0 + mf * 16 * D_SZ + ks * 128);
  }

  float minv[4][4];
  int   mini[4][4];
#pragma unroll
  for (int mf = 0; mf < 4; ++mf)
#pragma unroll
    for (int r4 = 0; r4 < 4; ++r4) { minv[mf][r4] = FLT_MAX; mini[mf][r4] = 0; }

  const int srow  = tid >> 5;
  const int sunit = tid & 31;
  const int soff  = (sunit ^ srow) << 4;
  auto stage = [&](int tt, int bb) {
#pragma unroll
    for (int p = 0; p < 4; ++p) {
      const int row = p * 8 + srow;
      const unsigned char* g =
          embf + (size_t)(codeBase + tt * 32 + row) * D_SZ + soff;
      __builtin_amdgcn_global_load_lds(
          (const __attribute__((address_space(1))) unsigned int*)g,
          (__attribute__((address_space(3))) unsigned int*)
              &etile[bb][(p * 8 + w * 2) * 512 + (lane << 4)],
          16, 0, 0);
    }
  };

  stage(0, 0);
  __syncthreads();

  const int swz = cr & 7;
  const char* lds0 = (const char*)etile[0];
  const char* lds1 = (const char*)etile[1];
  const float* esq_c = esqh + codeBase;

  for (int t = 0; t < 32; ++t) {
    const int bb = t & 1;
    if (t + 1 < 32) stage(t + 1, bb ^ 1);
    const char* buf = bb ? lds1 : lds0;
    const int tb = t * 32;

#pragma unroll
    for (int nf = 0; nf < 2; ++nf) {
      const int rb = (nf * 16 + cr) * 512;
      f32x4 acc4[4] = {};
#pragma unroll
      for (int ks = 0; ks < 4; ++ks) {
        const int ub = (ks << 3) + (cq << 1);
        const i32x4 lo =
            *reinterpret_cast<const i32x4*>(buf + rb + ((ub ^ swz) << 4));
        const i32x4 hi =
            *reinterpret_cast<const i32x4*>(buf + rb + (((ub + 1) ^ swz) << 4));
        const i32x8 bv = __builtin_shufflevector(lo, hi, 0, 1, 2, 3, 4, 5, 6, 7);
#pragma unroll
        for (int mf = 0; mf < 4; ++mf)
          acc4[mf] = __builtin_amdgcn_mfma_scale_f32_16x16x128_f8f6f4(
              a[mf][ks], bv, acc4[mf], 0, 0, 0, 0x7F, 0, 0x7F);
      }
      const int cl = tb + nf * 16 + cr;
      const float h = esq_c[cl];
      const int c = codeBase + cl;
#pragma unroll
      for (int mf = 0; mf < 4; ++mf)
#pragma unroll
        for (int r4 = 0; r4 < 4; ++r4) {
          const float s = h - acc4[mf][r4];
          if (s < minv[mf][r4]) { minv[mf][r4] = s; mini[mf][r4] = c; }
        }
    }
    __syncthreads();
  }

#pragma unroll
  for (int mf = 0; mf < 4; ++mf)
#pragma unroll
    for (int r4 = 0; r4 < 4; ++r4) {
      float v = minv[mf][r4];
      int   i = mini[mf][r4];
#pragma unroll
      for (int m = 1; m < 16; m <<= 1) {
        float ov = __shfl_xor(v, m, 64);
        int   oi = __shfl_xor(i, m, 64);
        if (ov < v || (ov == v && oi < i)) { v = ov; i = oi; }
      }
      if (cr == 0) {
        const int row = rowBase + w * 64 + mf * 16 + cq * 4 + r4;
        cand_val[(size_t)chunk * B_SZ + row] = v;
        cand_idx[(size_t)chunk * B_SZ + row] = i;
      }
    }
}

// ---------------------------------------------------------------------------
// Fused VQ finalize + loss: block handles 16 rows.  Lanes 0-15 reduce the 8
// chunk candidates for one row each (-> idx[] and LDS), then all 256 threads
// compute sum((zeb - embb[idx])^2) for those rows.  Codebook read as bf16
// (halves gather traffic; loss perturbation ~4e-7, negligible).
// ---------------------------------------------------------------------------
__global__ __launch_bounds__(256)
void vqloss_kernel(const unsigned short* __restrict__ zeb,
                   const unsigned short* __restrict__ embb,
                   const float* __restrict__ cv, const int* __restrict__ ci,
                   int* __restrict__ idx, float* __restrict__ accum) {
  __shared__ int   srow_idx[16];
  __shared__ float rsum[256];
  const int tid = threadIdx.x;
  const int r0  = blockIdx.x * 16;

  if (tid < 16) {
    const int r = r0 + tid;
    float bv = cv[r];
    int   bi = ci[r];
#pragma unroll
    for (int c = 1; c < 8; ++c) {
      const float v = cv[(size_t)c * B_SZ + r];
      const int  i2 = ci[(size_t)c * B_SZ + r];
      if (v < bv || (v == bv && i2 < bi)) { bv = v; bi = i2; }
    }
    srow_idx[tid] = bi;
    idx[r] = bi;
  }
  __syncthreads();

  const int lrow = tid >> 4;            // 0..15
  const int lu   = tid & 15;            // unit group
  const unsigned short* z = zeb + (size_t)(r0 + lrow) * D_SZ;
  const unsigned short* q = embb + (size_t)srow_idx[lrow] * D_SZ;
  float s = 0.f;
#pragma unroll
  for (int it = 0; it < 4; ++it) {
    const int d8 = lu + it * 16;        // 0..63
    bf16x8 zv = *reinterpret_cast<const bf16x8*>(z + d8 * 8);
    bf16x8 qv = *reinterpret_cast<const bf16x8*>(q + d8 * 8);
#pragma unroll
    for (int j = 0; j < 8; ++j) {
      const float d = bf2f((unsigned short)zv[j]) - bf2f((unsigned short)qv[j]);
      s += d * d;
    }
  }
  rsum[tid] = s;
  __syncthreads();
#pragma unroll
  for (int st = 128; st > 0; st >>= 1) {
    if (tid < st) rsum[tid] += rsum[tid + st];
    __syncthreads();
  }
  if (tid == 0) atomicAdd(accum + 1, rsum[0]);
}

// ---------------------------------------------------------------------------
__global__ void finalize_kernel(const float* __restrict__ accum,
                                float* __restrict__ out) {
  const float rl = -accum[0] / ((float)B_SZ * (float)DIN);
  const float el = accum[1] / (float)B_SZ;
  out[(size_t)B_SZ * DIN + 0] = rl;
  out[(size_t)B_SZ * DIN + 1] = el;
  out[(size_t)B_SZ * DIN + 2] = el;
}

// ---------------------------------------------------------------------------
extern "C" void kernel_launch(void* const* d_in, const int* in_sizes, int n_in,
                              void* d_out, int out_size, void* d_ws,
                              size_t ws_size, hipStream_t stream) {
  const float* x   = (const float*)d_in[0];
  const float* W1  = (const float*)d_in[1];
  const float* b1  = (const float*)d_in[2];
  const float* W2  = (const float*)d_in[3];
  const float* b2  = (const float*)d_in[4];
  const float* W3  = (const float*)d_in[5];
  const float* b3  = (const float*)d_in[6];
  const float* W4  = (const float*)d_in[7];
  const float* b4  = (const float*)d_in[8];
  const float* emb = (const float*)d_in[9];
  float* out = (float*)d_out;

  // ---- workspace layout ----
  char* wsb = (char*)d_ws;
  auto alloc = [&](size_t bytes) {
    char* p = wsb;
    wsb += (bytes + 255) & ~(size_t)255;
    return p;
  };
  unsigned short* zeb  = (unsigned short*)alloc((size_t)B_SZ * D_SZ * 2);
  unsigned short* embb = (unsigned short*)alloc((size_t)K_SZ * D_SZ * 2);
  char* regionB = alloc((size_t)B_SZ * H_P * 2);       // h1b, later h3b
  unsigned short* h1b = (unsigned short*)regionB;
  unsigned short* h3b = (unsigned short*)regionB;
  unsigned short* W1t = (unsigned short*)alloc((size_t)512 * DIN_P * 2);
  unsigned short* W2t = (unsigned short*)alloc((size_t)512 * H_P * 2);
  unsigned short* W3t = (unsigned short*)alloc((size_t)512 * D_SZ * 2);
  unsigned short* W4t = (unsigned short*)alloc((size_t)896 * H_P * 2);
  unsigned char* zef  = (unsigned char*)alloc((size_t)B_SZ * D_SZ);  // 8.4 MB
  unsigned char* embf = (unsigned char*)alloc((size_t)K_SZ * D_SZ);  // 4.2 MB
  float* esqh  = (float*)alloc((size_t)K_SZ * 4);
  float* accum = (float*)alloc(64);
  int*   idx   = (int*)alloc((size_t)B_SZ * 4);
  float* cand_val = (float*)alloc((size_t)8 * B_SZ * 4);
  int*   cand_idx = (int*)alloc((size_t)8 * B_SZ * 4);

  // 1) combined prep: 4 weight transposes + emb prep in one launch
  PrepArgs pa;
  pa.W[0] = W1;  pa.Wt[0] = W1t; pa.K[0] = DIN;  pa.N[0] = H_SZ;
  pa.Kpad[0] = DIN_P; pa.Npad[0] = 512; pa.gx[0] = 25;   // 25x16 = 400
  pa.W[1] = W2;  pa.Wt[1] = W2t; pa.K[1] = H_SZ; pa.N[1] = D_SZ;
  pa.Kpad[1] = H_P;   pa.Npad[1] = 512; pa.gx[1] = 13;   // 13x16 = 208
  pa.W[2] = W3;  pa.Wt[2] = W3t; pa.K[2] = D_SZ; pa.N[2] = H_SZ;
  pa.Kpad[2] = D_SZ;  pa.Npad[2] = 512; pa.gx[2] = 16;   // 16x16 = 256
  pa.W[3] = W4;  pa.Wt[3] = W4t; pa.K[3] = H_SZ; pa.N[3] = DIN;
  pa.Kpad[3] = H_P;   pa.Npad[3] = 896; pa.gx[3] = 13;   // 13x28 = 364
  pa.off[0] = 0; pa.off[1] = 400; pa.off[2] = 608; pa.off[3] = 864;
  pa.off[4] = 1228;
  pa.emb = emb; pa.embb = embb; pa.embf = embf; pa.esqh = esqh;
  pa.accum = accum;
  prep_kernel<<<1228 + K_SZ / 4, 256, 0, stream>>>(pa);
  // 2) h1 = relu(x @ W1 + b1)   (A converted fp32->bf16 in staging)
  mgemm_kernel<1, false, false, false, false, true>
      <<<dim3(4, B_SZ / 128), 256, 0, stream>>>(
      nullptr, x, W1t, b1, h1b, H_SZ, DIN_P, H_P, nullptr, nullptr, nullptr,
      nullptr);
  // 3) z_e = h1 @ W2 + b2  (bf16 zeb + fp8 zef)
  mgemm_kernel<0, false, false, false, true, false>
      <<<dim3(4, B_SZ / 128), 256, 0, stream>>>(
      h1b, nullptr, W2t, b2, zeb, D_SZ, H_P, D_SZ, nullptr, nullptr, nullptr,
      zef);
  // 4) VQ argmin (MX fp8 MFMA)
  vq_mfma_kernel<<<512, 256, 0, stream>>>(zef, embf, esqh, cand_val, cand_idx);
  // 5) fused finalize + embed/commit loss (bf16 codebook)
  vqloss_kernel<<<B_SZ / 16, 256, 0, stream>>>(zeb, embb, cand_val, cand_idx,
                                               idx, accum);
  // 6) h3 = relu(emb[idx] @ W3 + b3)
  mgemm_kernel<1, true, false, false, false, false>
      <<<dim3(4, B_SZ / 128), 256, 0, stream>>>(
      embb, nullptr, W3t, b3, h3b, H_SZ, D_SZ, H_P, idx, nullptr, nullptr,
      nullptr);
  // 7) x_reconst = sigmoid(h3 @ W4 + b4), fused fast BCE
  mgemm_kernel<2, false, true, true, false, false>
      <<<dim3(7, B_SZ / 128), 256, 0, stream>>>(
      h3b, nullptr, W4t, b4, out, DIN, H_P, DIN, nullptr, x, accum, nullptr);
  // 8) scalars
  finalize_kernel<<<1, 1, 0, stream>>>(accum, out);
}